// Round 12
// baseline (1465.941 us; speedup 1.0000x reference)
//
#include <hip/hip_runtime.h>
#include <math.h>

typedef unsigned int u32;
typedef unsigned short u16;
typedef __attribute__((ext_vector_type(8))) short bf16x8;
typedef __attribute__((ext_vector_type(4))) float f32x4;

#define E_TOT 100000
constexpr int NS = 128, DIM = 320;

constexpr float SC_S_SCALE = 0.022097086912079608f;  // 1/sqrt(128*16)
constexpr float SC_V_SCALE = 0.03125f;               // 1/32
constexpr float INV_SQRT128 = 0.08838834764831845f;
constexpr float INV_8 = 0.125f;
constexpr float INV_S384 = 0.05103103630798288f;
constexpr float INV_24 = 0.041666666666666664f;
constexpr float INV_S192 = 0.07216878364870323f;
constexpr float RSQRT2 = 0.7071067811865476f;

#define MFMA __builtin_amdgcn_mfma_f32_16x16x32_bf16
#define F4Z (f32x4){0.f, 0.f, 0.f, 0.f}

__device__ __forceinline__ float sigmoidf_(float x) { return 1.0f / (1.0f + __expf(-x)); }
__device__ __forceinline__ float siluf_(float x) { return x * sigmoidf_(x); }
__device__ __forceinline__ float bf2f(u16 h) {
  u32 u = ((u32)h) << 16;
  return __builtin_bit_cast(float, u);
}
__device__ __forceinline__ u16 f2bf(float f) {
  u32 u = __builtin_bit_cast(u32, f);
  return (u16)((u + 0x7fffu + ((u >> 16) & 1u)) >> 16);
}
__device__ __forceinline__ void gl_lds16(const void* g, void* l) {
  __builtin_amdgcn_global_load_lds((const __attribute__((address_space(1))) u32*)g,
                                   (__attribute__((address_space(3))) u32*)l, 16, 0, 0);
}
__device__ __forceinline__ bf16x8 pack8(float4 r0, float4 r1, float s) {
  bf16x8 a;
  a[0] = (short)f2bf(r0.x * s); a[1] = (short)f2bf(r0.y * s);
  a[2] = (short)f2bf(r0.z * s); a[3] = (short)f2bf(r0.w * s);
  a[4] = (short)f2bf(r1.x * s); a[5] = (short)f2bf(r1.y * s);
  a[6] = (short)f2bf(r1.z * s); a[7] = (short)f2bf(r1.w * s);
  return a;
}
// swizzled bf16 LDS helpers (XOR byte bits 4-6 with row&7); rowB multiple of 128
__device__ __forceinline__ void stb(char* base, int row, int rowB, int colByte, u16 v) {
  *(u16*)(base + row * rowB + (colByte ^ ((row & 7) << 4))) = v;
}
__device__ __forceinline__ u16 ldbs(const char* base, int row, int rowB, int colByte) {
  return *(const u16*)(base + row * rowB + (colByte ^ ((row & 7) << 4)));
}
__device__ __forceinline__ bf16x8 ldb8(const char* base, int row, int rowB, int colByte) {
  return *(const bf16x8*)(base + row * rowB + (colByte ^ ((row & 7) << 4)));
}
__device__ __forceinline__ void stb16(char* base, int row, int rowB, int colByte, bf16x8 v) {
  *(bf16x8*)(base + row * rowB + (colByte ^ ((row & 7) << 4))) = v;
}

// ---------------- weight arena (element offsets) ----------------
#define OW_W2S   0        /* [128 u][2048 k=s*128+v]  (sc_s, SC_S_SCALE folded) */
#define OW_BTV   262144   /* [64 u][1024 k=s*64+v]    (sc_v, SC_V_SCALE folded) */
// fragment-linear: elem = (nt*(K/32)+kc)*512 + lane*8 + j
#define OW_PRE0  327680   /* N=128 K=128 */
#define OW_PRE1X 344064   /* N=192 K=192 block-diag */
#define OW_SS    380928   /* N=192 K=384 */
#define OW_VS    454656   /* N=192 K=192 (svh path) */
#define OW_SV    491520   /* N=64  K=384 */
#define OW_VVX   516096   /* N=192 K=576 block-diag */
#define OW_F1    626688   /* N=64  K=128 */
#define OW_F2    634880   /* N=64  K=64  */
#define OW_F3    638976   /* N=192 K=64  */
#define OW_P0    651264   /* N=128 K=128 */
#define OW_P1X   667648   /* N=192 K=192 block-diag */
#define OW_END   704512

// ---------------- K0: weight prep ----------------
__device__ __forceinline__ void frag_uc(int oo, int K, int& up, int& c) {
  int per = (K >> 5) << 9;
  int nt = oo / per, r = oo % per;
  int kc = r >> 9, r2 = r & 511;
  int ln = r2 >> 3, j = r2 & 7;
  up = nt * 16 + (ln & 15);
  c = kc * 32 + (ln >> 4) * 8 + j;
}

__global__ __launch_bounds__(256) void k_prep(
    const float* __restrict__ Wsc_s, const float* __restrict__ Wsc_v,
    const float* __restrict__ Wpre0, const float* __restrict__ Wpre1,
    const float* __restrict__ Wss, const float* __restrict__ Wvs,
    const float* __restrict__ Wsv, const float* __restrict__ Wvv,
    const float* __restrict__ Wf1, const float* __restrict__ Wf2,
    const float* __restrict__ Wf3, const float* __restrict__ Wpost0,
    const float* __restrict__ Wpost1, u16* __restrict__ dst) {
  int o = blockIdx.x * 256 + threadIdx.x;
  if (o >= OW_END) return;
  float v;
  int up, c;
  if (o < OW_BTV) {
    int u = o >> 11, k = o & 2047, s = k >> 7, vv = k & 127;
    v = Wsc_s[((size_t)(vv * 16 + s)) * 128 + u] * SC_S_SCALE;
  } else if (o < OW_PRE0) {
    int oo = o - OW_BTV; int u = oo >> 10, k = oo & 1023, s = k >> 6, vv = k & 63;
    v = Wsc_v[((size_t)(vv * 16 + s)) * 64 + u] * SC_V_SCALE;
  } else if (o < OW_PRE1X) {
    frag_uc(o - OW_PRE0, 128, up, c);
    v = Wpre0[c * 128 + up] * INV_SQRT128;
  } else if (o < OW_SS) {
    frag_uc(o - OW_PRE1X, 192, up, c);
    int u = up / 3, m = up % 3, vv = c / 3, mp = c % 3;
    v = (m == mp) ? Wpre1[vv * 64 + u] * INV_8 : 0.f;
  } else if (o < OW_VS) {
    frag_uc(o - OW_SS, 384, up, c);
    v = Wss[c * 192 + up] * (INV_S384 * RSQRT2);
  } else if (o < OW_SV) {
    frag_uc(o - OW_VS, 192, up, c);
    v = Wvs[c * 192 + up] * (INV_24 * RSQRT2);
  } else if (o < OW_VVX) {
    frag_uc(o - OW_SV, 384, up, c);
    v = Wsv[c * 64 + up] * (INV_S384 * RSQRT2);
  } else if (o < OW_F1) {
    frag_uc(o - OW_VVX, 576, up, c);
    int u = up / 3, m = up % 3, p = c / 192, r = c % 192, vv = r / 3, mp = r % 3;
    v = (m == mp) ? Wvv[(p * 64 + vv) * 64 + u] * (INV_S192 * RSQRT2) : 0.f;
  } else if (o < OW_F2) {
    frag_uc(o - OW_F1, 128, up, c);
    v = Wf1[c * 64 + up];
  } else if (o < OW_F3) {
    frag_uc(o - OW_F2, 64, up, c);
    v = Wf2[c * 64 + up];
  } else if (o < OW_P0) {
    frag_uc(o - OW_F3, 64, up, c);
    v = Wf3[c * 192 + up];
  } else if (o < OW_P1X) {
    frag_uc(o - OW_P0, 128, up, c);
    v = Wpost0[c * 128 + up] * INV_SQRT128;
  } else {
    frag_uc(o - OW_P1X, 192, up, c);
    int u = up / 3, m = up % 3, vv = c / 3, mp = c % 3;
    v = (m == mp) ? Wpost1[vv * 64 + u] * INV_8 : 0.f;
  }
  dst[o] = f2bf(v);
}

// ---------------- K1: merged sc — 512 thr, double-buffered B staging ----------------
#define MEs 64
__global__ __launch_bounds__(512, 4) void k_sc(
    const float* __restrict__ edge_fea, const float* __restrict__ ohp,
    const u16* __restrict__ W2s, const u16* __restrict__ Btv,
    float* __restrict__ out) {
  __shared__ char esB[16384];   // [64][256B] swizzled
  __shared__ char evT[24576];   // [192 r=3e+m][128B] swizzled, col=v
  __shared__ float ohL[64][16];
  __shared__ char Bbuf[32768];  // sc_s: 2×16K halves; sc_v: 2×8K (low 16K)
  const int t = threadIdx.x, lane = t & 63, ww = t >> 6;  // 8 waves
  const int l15 = lane & 15, q8 = lane >> 4, q4 = q8 << 2, cbl = q8 << 4;
  const int e0 = blockIdx.x * MEs;
  const int nE = min(MEs, E_TOT - e0);
  const int wc = ww & 3, wr = ww >> 2;

  // issue sc_s half-chunk (s, h): rows u_g = 64h..64h+63, 16KB -> buf
  auto issue_s = [&](int s, int h, char* buf) {
    const char* sb = (const char*)W2s + (size_t)(64 * h) * 4096 + s * 256;
    #pragma unroll
    for (int it = 0; it < 2; ++it) {
      int n = it * 512 + t;
      int u = n >> 4, gp = n & 15, g = gp ^ (u & 7);
      gl_lds16(sb + (size_t)u * 4096 + g * 16, buf + n * 16);
    }
  };
  // issue sc_v chunk s: 64 rows x 128B = 8KB -> buf
  auto issue_v = [&](int s, char* buf) {
    int n = t;
    int u = n >> 3, gp = n & 7, g = gp ^ (u & 7);
    gl_lds16((const char*)Btv + (size_t)u * 2048 + s * 128 + g * 16, buf + n * 16);
  };

  // stage es/ev/oh once + issue phase-0 loads (drained by the same barrier)
  issue_s(0, 0, Bbuf);
  for (int o = t; o < 2560; o += 512) {
    int c = o % 40, e = o / 40;
    float4 r0 = make_float4(0.f, 0.f, 0.f, 0.f), r1 = r0;
    if (e < nE) {
      const float* src = edge_fea + (size_t)(e0 + e) * 320 + c * 8;
      r0 = *(const float4*)src; r1 = *(const float4*)(src + 4);
    }
    if (c < 16) stb16(esB, e, 256, c * 16, pack8(r0, r1, 1.f));
    else {
      int base = (c - 16) * 8;
      float vals[8] = {r0.x, r0.y, r0.z, r0.w, r1.x, r1.y, r1.z, r1.w};
      #pragma unroll
      for (int z = 0; z < 8; ++z) {
        int cc = base + z;
        stb(evT, 3 * e + cc % 3, 128, (cc / 3) * 2, f2bf(vals[z]));
      }
    }
  }
  for (int o = t; o < 1024; o += 512) {
    int e = o >> 4, s = o & 15;
    ohL[e][s] = (e < nE) ? ohp[(size_t)(e0 + e) * 16 + s] : 0.f;
  }
  __syncthreads();

  // ---- sc_s: 32 phases (p = s*2 + h), wave owns col wc per half, rows 2wr..2wr+1 ----
  {
    f32x4 acc[2][2];  // [row i][half h]
    acc[0][0] = F4Z; acc[0][1] = F4Z; acc[1][0] = F4Z; acc[1][1] = F4Z;
    for (int p = 0; p < 32; ++p) {
      char* buf = Bbuf + ((p & 1) << 14);
      if (p + 1 < 32) issue_s((p + 1) >> 1, (p + 1) & 1, Bbuf + (((p + 1) & 1) << 14));
      else issue_v(0, Bbuf);  // prefetch sc_v phase 0 into low 8K (read last in p=30)
      int s = p >> 1, h = p & 1;
      f32x4 tmp[2] = {F4Z, F4Z};
      #pragma unroll
      for (int ks = 0; ks < 4; ++ks) {
        bf16x8 b = ldb8(buf, wc * 16 + l15, 256, ks * 64 + cbl);
        #pragma unroll
        for (int i = 0; i < 2; ++i) {
          bf16x8 a = ldb8(esB, (2 * wr + i) * 16 + l15, 256, ks * 64 + cbl);
          tmp[i] = MFMA(a, b, tmp[i], 0, 0, 0);
        }
      }
      #pragma unroll
      for (int i = 0; i < 2; ++i)
        #pragma unroll
        for (int j = 0; j < 4; ++j)
          acc[i][h][j] += ohL[(2 * wr + i) * 16 + q4 + j][s] * tmp[i][j];
      __syncthreads();
    }
    #pragma unroll
    for (int i = 0; i < 2; ++i)
      #pragma unroll
      for (int h = 0; h < 2; ++h) {
        int u = (h * 4 + wc) * 16 + l15;
        #pragma unroll
        for (int j = 0; j < 4; ++j) {
          int e = (2 * wr + i) * 16 + q4 + j;
          if (e < nE) out[(size_t)(e0 + e) * DIM + u] = acc[i][h][j];
        }
      }
  }

  // ---- sc_v: 16 phases, wave owns col wc, rows 6wr..6wr+5 ----
  {
    const int rb = wr * 6;
    f32x4 acc[6] = {F4Z, F4Z, F4Z, F4Z, F4Z, F4Z};
    for (int s = 0; s < 16; ++s) {
      char* buf = Bbuf + ((s & 1) << 13);
      if (s + 1 < 16) issue_v(s + 1, Bbuf + (((s + 1) & 1) << 13));
      f32x4 tmp[6] = {F4Z, F4Z, F4Z, F4Z, F4Z, F4Z};
      #pragma unroll
      for (int ks = 0; ks < 2; ++ks) {
        bf16x8 b = ldb8(buf, wc * 16 + l15, 128, ks * 64 + cbl);
        #pragma unroll
        for (int i = 0; i < 6; ++i) {
          bf16x8 a = ldb8(evT, (rb + i) * 16 + l15, 128, ks * 64 + cbl);
          tmp[i] = MFMA(a, b, tmp[i], 0, 0, 0);
        }
      }
      #pragma unroll
      for (int i = 0; i < 6; ++i)
        #pragma unroll
        for (int j = 0; j < 4; ++j) {
          int r = (rb + i) * 16 + q4 + j;
          acc[i][j] += ohL[(r * 683) >> 11][s] * tmp[i][j];
        }
      __syncthreads();
    }
    int u = wc * 16 + l15;
    #pragma unroll
    for (int i = 0; i < 6; ++i)
      #pragma unroll
      for (int j = 0; j < 4; ++j) {
        int r = (rb + i) * 16 + q4 + j;
        int e = (r * 683) >> 11, m = r - 3 * e;
        if (e < nE) out[(size_t)(e0 + e) * DIM + 128 + u * 3 + m] = acc[i][j];
      }
  }
}

// ---------------- K2: fused chain + stats, M=32, 512 thr, 2 blocks/CU (verified R9) ----------------
#define A_SZ 78976
__global__ __launch_bounds__(512, 4) void k_chain(
    const float* __restrict__ node_fea, const float* __restrict__ edge_sh,
    const float* __restrict__ edge_fea, const float* __restrict__ elen,
    const int* __restrict__ eidx, const int* __restrict__ batch,
    const u16* __restrict__ wbf,
    const float* __restrict__ bpre0, const float* __restrict__ bf1,
    const float* __restrict__ bf2, const float* __restrict__ bf3,
    const float* __restrict__ bpost0, float* __restrict__ out,
    float* __restrict__ statsB) {
  __shared__ char AR[A_SZ];
  float* shF = (float*)(AR + 77824);  // [32][4]
  int* ijL = (int*)(AR + 78336);      // [2][32]
  float* sS  = (float*)(AR + 78592);  // [32] z-sum (s part)
  float* sS2 = (float*)(AR + 78720);  // [32] z2-sum (s part)
  float* sV  = (float*)(AR + 78848);  // [32] z2-sum (v part)
  const int t = threadIdx.x, lane = t & 63, wv = t >> 6;
  const int l15 = lane & 15, q8 = lane >> 4, q4 = q8 << 2, cbl = q8 << 4;
  const int e0 = blockIdx.x * 32;

#define SA(b) (AR + (b) * 8192)
#define VA(b) (AR + 24576 + (b) * 12288)
  char* wB = AR;
  char* zsB = AR + 12288;
  char* gateB = AR + 20480;
  char* zvB = AR + 24576;
  char* t1B = AR + 61440;   // svh K 128..191 during [BAR1c, BAR2a]; t1 after BAR2a
  char* hB = AR + 65536;
  char* elB = AR + 69632;   // elen during P1; svh K 0..127 after BAR1b

  if (t < 64) { int p = t >> 5, e = t & 31; ijL[p * 32 + e] = eidx[p * E_TOT + e0 + e]; }
  if (t >= 64 && t < 192) { int o = t - 64; shF[o] = edge_sh[(size_t)e0 * 4 + o]; }
  if (t >= 192 && t < 288) ((float*)(AR + 78592))[t - 192] = 0.f;
  __syncthreads();

  // ---- P0: staging ----
  for (int o = t; o < 1280; o += 512) {
    int c = o % 40, e = o / 40;
    const float* src = edge_fea + (size_t)(e0 + e) * 320 + c * 8;
    float4 r0 = *(const float4*)src, r1 = *(const float4*)(src + 4);
    bf16x8 v = pack8(r0, r1, 1.f);
    if (c < 16) stb16(SA(2), e, 256, c * 16, v);
    else        stb16(VA(2), e, 384, (c - 16) * 16, v);
  }
  for (int o = t; o < 2560; o += 512) {
    int c = o % 40, tmp = o / 40, e = tmp & 31, p = tmp >> 5;
    const float* src = node_fea + (size_t)ijL[p * 32 + e] * 320 + c * 8;
    float4 r0 = *(const float4*)src, r1 = *(const float4*)(src + 4);
    bf16x8 v = pack8(r0, r1, 1.f);
    if (c < 16) stb16(SA(p), e, 256, c * 16, v);
    else        stb16(VA(p), e, 384, (c - 16) * 16, v);
  }
  for (int o = t; o < 512; o += 512) {
    int c = o & 15, e = o >> 4;
    const float* src = elen + (size_t)(e0 + e) * 128 + c * 8;
    float4 r0 = *(const float4*)src, r1 = *(const float4*)(src + 4);
    stb16(elB, e, 256, c * 16, pack8(r0, r1, 1.f));
  }
  __syncthreads();

  // ---- P1: v-pre (w0-3) | s-pre (w4-5) | h1 (w6-7) ----
  f32x4 acc[8];
  #pragma unroll
  for (int a = 0; a < 8; ++a) acc[a] = F4Z;
  if (wv < 4) {
    for (int kc = 0; kc < 6; ++kc) {
      bf16x8 a0 = ldb8(VA(2), l15, 384, kc * 64 + cbl);
      bf16x8 a1 = ldb8(VA(2), 16 + l15, 384, kc * 64 + cbl);
      #pragma unroll
      for (int i = 0; i < 3; ++i) {
        int nt = wv * 3 + i;
        bf16x8 b = *(const bf16x8*)(wbf + OW_PRE1X + (((size_t)nt * 6 + kc) << 9) + lane * 8);
        acc[i] = MFMA(a0, b, acc[i], 0, 0, 0);
        acc[3 + i] = MFMA(a1, b, acc[3 + i], 0, 0, 0);
      }
    }
  } else if (wv < 6) {
    for (int kc = 0; kc < 4; ++kc) {
      bf16x8 a0 = ldb8(SA(2), l15, 256, kc * 64 + cbl);
      bf16x8 a1 = ldb8(SA(2), 16 + l15, 256, kc * 64 + cbl);
      #pragma unroll
      for (int i = 0; i < 4; ++i) {
        int nt = (wv - 4) * 4 + i;
        bf16x8 b = *(const bf16x8*)(wbf + OW_PRE0 + (((size_t)nt * 4 + kc) << 9) + lane * 8);
        acc[i] = MFMA(a0, b, acc[i], 0, 0, 0);
        acc[4 + i] = MFMA(a1, b, acc[4 + i], 0, 0, 0);
      }
    }
  } else {
    for (int kc = 0; kc < 4; ++kc) {
      bf16x8 a0 = ldb8(elB, l15, 256, kc * 64 + cbl);
      bf16x8 a1 = ldb8(elB, 16 + l15, 256, kc * 64 + cbl);
      #pragma unroll
      for (int i = 0; i < 2; ++i) {
        int nt = (wv - 6) * 2 + i;
        bf16x8 b = *(const bf16x8*)(wbf + OW_F1 + (((size_t)nt * 4 + kc) << 9) + lane * 8);
        acc[i] = MFMA(a0, b, acc[i], 0, 0, 0);
        acc[2 + i] = MFMA(a1, b, acc[2 + i], 0, 0, 0);
      }
    }
  }
  __syncthreads();  // BAR1a
  if (wv < 4) {
    #pragma unroll
    for (int mt = 0; mt < 2; ++mt)
      #pragma unroll
      for (int i = 0; i < 3; ++i) {
        int up = (wv * 3 + i) * 16 + l15;
        #pragma unroll
        for (int j = 0; j < 4; ++j)
          stb(VA(2), mt * 16 + q4 + j, 384, up * 2, f2bf(acc[mt * 3 + i][j]));
      }
  } else if (wv < 6) {
    #pragma unroll
    for (int i = 0; i < 4; ++i) {
      int u = ((wv - 4) * 4 + i) * 16 + l15;
      float bias = bpre0[u];
      #pragma unroll
      for (int mt = 0; mt < 2; ++mt)
        #pragma unroll
        for (int j = 0; j < 4; ++j)
          stb(SA(2), mt * 16 + q4 + j, 256, u * 2, f2bf(acc[mt * 4 + i][j] + bias));
    }
  } else {
    #pragma unroll
    for (int i = 0; i < 2; ++i) {
      int u = ((wv - 6) * 2 + i) * 16 + l15;
      float bias = bf1[u];
      #pragma unroll
      for (int mt = 0; mt < 2; ++mt)
        #pragma unroll
        for (int j = 0; j < 4; ++j)
          stb(hB, mt * 16 + q4 + j, 128, u * 2, f2bf(siluf_(acc[mt * 2 + i][j] + bias)));
    }
  }
  __syncthreads();  // BAR1b

  // ---- P1.5: svh[e][K] -> elB (K<128) / t1B (K>=128) ----
  for (int o = t; o < 32 * 192; o += 512) {
    int e = o / 192, K = o % 192;
    int src = K >> 6, kk = K & 63;
    const char* vb = VA(src);
    float x0 = bf2f(ldbs(vb, e, 384, (3 * kk + 0) * 2));
    float x1 = bf2f(ldbs(vb, e, 384, (3 * kk + 1) * 2));
    float x2 = bf2f(ldbs(vb, e, 384, (3 * kk + 2) * 2));
    float sv = x0 * shF[e * 4 + 1] + x1 * shF[e * 4 + 2] + x2 * shF[e * 4 + 3];
    if (K < 128) stb(elB, e, 256, K * 2, f2bf(sv));
    else stb(t1B, e, 128, (K - 128) * 2, f2bf(sv));
  }
  __syncthreads();  // BAR1c

  // ---- P2: out_s (w0-5, acc4) | t1 (w6-7, acc4) ; h2 (all, acc1) ----
  f32x4 os[4] = {F4Z, F4Z, F4Z, F4Z};
  f32x4 h2a = F4Z;
  {
    const int hmt = wv >> 2, hnt = wv & 3;
    #pragma unroll
    for (int kc = 0; kc < 2; ++kc) {
      bf16x8 a = ldb8(hB, hmt * 16 + l15, 128, kc * 64 + cbl);
      bf16x8 b = *(const bf16x8*)(wbf + OW_F2 + (((size_t)hnt * 2 + kc) << 9) + lane * 8);
      h2a = MFMA(a, b, h2a, 0, 0, 0);
    }
  }
  if (wv < 6) {
    for (int kc = 0; kc < 12; ++kc) {
      int buf = kc >> 2, cB = (kc & 3) * 64 + cbl;
      bf16x8 a0 = ldb8(SA(buf), l15, 256, cB);
      bf16x8 a1 = ldb8(SA(buf), 16 + l15, 256, cB);
      #pragma unroll
      for (int i = 0; i < 2; ++i) {
        int nt = wv * 2 + i;
        bf16x8 b = *(const bf16x8*)(wbf + OW_SS + (((size_t)nt * 12 + kc) << 9) + lane * 8);
        os[i] = MFMA(a0, b, os[i], 0, 0, 0);
        os[2 + i] = MFMA(a1, b, os[2 + i], 0, 0, 0);
      }
    }
    #pragma unroll
    for (int mt = 0; mt < 2; ++mt)
      #pragma unroll
      for (int i = 0; i < 2; ++i)
        #pragma unroll
        for (int j = 0; j < 4; ++j)
          os[mt * 2 + i][j] *= shF[(mt * 16 + q4 + j) * 4 + 0];
    for (int kc = 0; kc < 6; ++kc) {
      const char* sb_ = (kc < 4) ? elB : t1B;
      int rB = (kc < 4) ? 256 : 128;
      int cB = ((kc < 4) ? kc : (kc - 4)) * 64 + cbl;
      bf16x8 a0 = ldb8(sb_, l15, rB, cB);
      bf16x8 a1 = ldb8(sb_, 16 + l15, rB, cB);
      #pragma unroll
      for (int i = 0; i < 2; ++i) {
        int nt = wv * 2 + i;
        bf16x8 b = *(const bf16x8*)(wbf + OW_VS + (((size_t)nt * 6 + kc) << 9) + lane * 8);
        os[i] = MFMA(a0, b, os[i], 0, 0, 0);
        os[2 + i] = MFMA(a1, b, os[2 + i], 0, 0, 0);
      }
    }
  } else {
    for (int kc = 0; kc < 12; ++kc) {
      int buf = kc >> 2, cB = (kc & 3) * 64 + cbl;
      bf16x8 a0 = ldb8(SA(buf), l15, 256, cB);
      bf16x8 a1 = ldb8(SA(buf), 16 + l15, 256, cB);
      #pragma unroll
      for (int i = 0; i < 2; ++i) {
        int nt = (wv - 6) * 2 + i;
        bf16x8 b = *(const bf16x8*)(wbf + OW_SV + (((size_t)nt * 12 + kc) << 9) + lane * 8);
        os[i] = MFMA(a0, b, os[i], 0, 0, 0);
        os[2 + i] = MFMA(a1, b, os[2 + i], 0, 0, 0);
      }
    }
  }
  __syncthreads();  // BAR2a
  {
    const int hmt = wv >> 2;
    int u = (wv & 3) * 16 + l15;
    float bias = bf2[u];
    #pragma unroll
    for (int j = 0; j < 4; ++j)
      stb(hB, hmt * 16 + q4 + j, 128, u * 2, f2bf(siluf_(h2a[j] + bias)));
  }
  if (wv >= 6) {
    #pragma unroll
    for (int mt = 0; mt < 2; ++mt)
      #pragma unroll
      for (int i = 0; i < 2; ++i) {
        int u = ((wv - 6) * 2 + i) * 16 + l15;
        #pragma unroll
        for (int j = 0; j < 4; ++j)
          stb(t1B, mt * 16 + q4 + j, 128, u * 2, f2bf(os[mt * 2 + i][j]));
      }
  }
  __syncthreads();  // BAR2b

  // ---- P3: w = h2@Wf3 + bf3 ----
  {
    f32x4 wa[3] = {F4Z, F4Z, F4Z};
    const int mtw = wv >> 2;
    #pragma unroll
    for (int kc = 0; kc < 2; ++kc) {
      bf16x8 a = ldb8(hB, mtw * 16 + l15, 128, kc * 64 + cbl);
      #pragma unroll
      for (int i = 0; i < 3; ++i) {
        int nt = (wv & 3) * 3 + i;
        bf16x8 b = *(const bf16x8*)(wbf + OW_F3 + (((size_t)nt * 2 + kc) << 9) + lane * 8);
        wa[i] = MFMA(a, b, wa[i], 0, 0, 0);
      }
    }
    #pragma unroll
    for (int i = 0; i < 3; ++i) {
      int up = ((wv & 3) * 3 + i) * 16 + l15;
      float bias = bf3[up];
      #pragma unroll
      for (int j = 0; j < 4; ++j)
        stb(wB, mtw * 16 + q4 + j, 384, up * 2, f2bf(wa[i][j] + bias));
    }
  }
  __syncthreads();  // BAR3

  // ---- P4: gating (w0-5) + out_v MFMAs (all) ----
  if (wv < 6) {
    #pragma unroll
    for (int mt = 0; mt < 2; ++mt)
      #pragma unroll
      for (int i = 0; i < 2; ++i) {
        int up = (wv * 2 + i) * 16 + l15;
        #pragma unroll
        for (int j = 0; j < 4; ++j) {
          int e = mt * 16 + q4 + j;
          float w_ = bf2f(ldbs(wB, e, 384, up * 2));
          float o_ = os[mt * 2 + i][j];
          if (up < 128) stb(zsB, e, 256, up * 2, f2bf(siluf_(o_) * w_));
          else stb(gateB, e, 128, (up - 128) * 2, f2bf(sigmoidf_(o_) * w_));
        }
      }
  }
  f32x4 ov[3] = {F4Z, F4Z, F4Z};
  {
    const int mtv = wv >> 2;
    for (int p = 0; p < 3; ++p)
      for (int kc6 = 0; kc6 < 6; ++kc6) {
        int cB = kc6 * 64 + cbl;
        bf16x8 a = ldb8(VA(p), mtv * 16 + l15, 384, cB);
        int kcg = p * 6 + kc6;
        #pragma unroll
        for (int i = 0; i < 3; ++i) {
          int nt = (wv & 3) * 3 + i;
          bf16x8 b = *(const bf16x8*)(wbf + OW_VVX + (((size_t)nt * 18 + kcg) << 9) + lane * 8);
          ov[i] = MFMA(a, b, ov[i], 0, 0, 0);
        }
      }
  }
  __syncthreads();  // BAR4
  {
    const int mtv = wv >> 2;
    #pragma unroll
    for (int i = 0; i < 3; ++i) {
      int up = ((wv & 3) * 3 + i) * 16 + l15;
      int u = (up * 683) >> 11, m = up - 3 * u;
      #pragma unroll
      for (int j = 0; j < 4; ++j) {
        int e = mtv * 16 + q4 + j;
        float t1v = bf2f(ldbs(t1B, e, 128, u * 2));
        float g = bf2f(ldbs(gateB, e, 128, u * 2));
        float val = ov[i][j] * shF[e * 4 + 0] + t1v * shF[e * 4 + 1 + m];
        stb(zvB, e, 384, up * 2, f2bf(val * g));
      }
    }
  }
  __syncthreads();  // BAR5

  // ---- P5: post0 + post1, RMW onto sc in d_out + per-edge stats ----
  {
    f32x4 p0[2] = {F4Z, F4Z};
    #pragma unroll
    for (int kc = 0; kc < 4; ++kc) {
      int cB = kc * 64 + cbl;
      bf16x8 a0 = ldb8(zsB, l15, 256, cB);
      bf16x8 a1 = ldb8(zsB, 16 + l15, 256, cB);
      bf16x8 b = *(const bf16x8*)(wbf + OW_P0 + (((size_t)wv * 4 + kc) << 9) + lane * 8);
      p0[0] = MFMA(a0, b, p0[0], 0, 0, 0);
      p0[1] = MFMA(a1, b, p0[1], 0, 0, 0);
    }
    int u = wv * 16 + l15;
    float bias = bpost0[u];
    float s1p[8], s2p[8];
    #pragma unroll
    for (int mt = 0; mt < 2; ++mt)
      #pragma unroll
      for (int j = 0; j < 4; ++j) {
        size_t o = (size_t)(e0 + mt * 16 + q4 + j) * DIM + u;
        float z = out[o] + p0[mt][j] + bias;
        out[o] = z;
        s1p[mt * 4 + j] = z;
        s2p[mt * 4 + j] = z * z;
      }
    #pragma unroll
    for (int msk = 1; msk < 16; msk <<= 1)
      #pragma unroll
      for (int k = 0; k < 8; ++k) {
        s1p[k] += __shfl_xor(s1p[k], msk);
        s2p[k] += __shfl_xor(s2p[k], msk);
      }
    if (l15 == 0) {
      #pragma unroll
      for (int mt = 0; mt < 2; ++mt)
        #pragma unroll
        for (int j = 0; j < 4; ++j) {
          int e = mt * 16 + q4 + j;
          atomicAdd(&sS[e], s1p[mt * 4 + j]);
          atomicAdd(&sS2[e], s2p[mt * 4 + j]);
        }
    }
  }
  {
    f32x4 p1[3] = {F4Z, F4Z, F4Z};
    const int mtv = wv >> 2;
    #pragma unroll
    for (int kc = 0; kc < 6; ++kc) {
      int cB = kc * 64 + cbl;
      bf16x8 a = ldb8(zvB, mtv * 16 + l15, 384, cB);
      #pragma unroll
      for (int i = 0; i < 3; ++i) {
        int nt = (wv & 3) * 3 + i;
        bf16x8 b = *(const bf16x8*)(wbf + OW_P1X + (((size_t)nt * 6 + kc) << 9) + lane * 8);
        p1[i] = MFMA(a, b, p1[i], 0, 0, 0);
      }
    }
    float svp[4] = {0.f, 0.f, 0.f, 0.f};
    #pragma unroll
    for (int i = 0; i < 3; ++i) {
      int up = ((wv & 3) * 3 + i) * 16 + l15;
      #pragma unroll
      for (int j = 0; j < 4; ++j) {
        size_t o = (size_t)(e0 + mtv * 16 + q4 + j) * DIM + 128 + up;
        float z = out[o] + p1[i][j];
        out[o] = z;
        svp[j] += z * z;
      }
    }
    #pragma unroll
    for (int msk = 1; msk < 16; msk <<= 1)
      #pragma unroll
      for (int j = 0; j < 4; ++j) svp[j] += __shfl_xor(svp[j], msk);
    if (l15 == 0) {
      #pragma unroll
      for (int j = 0; j < 4; ++j)
        atomicAdd(&sV[mtv * 16 + q4 + j], svp[j]);
    }
  }
  __syncthreads();  // BAR6
  if (t < 32) {
    int g = batch[ijL[t]];
    float* sb = statsB + ((size_t)(blockIdx.x & 63)) * 64 + g * 4;
    atomicAdd(sb + 0, 1.0f);
    atomicAdd(sb + 1, sS[t]);
    atomicAdd(sb + 2, sS2[t]);
    atomicAdd(sb + 3, sV[t]);
  }
#undef SA
#undef VA
}

// ---------------- K4: normalize + residual (float4; reduces 64 stat buckets) ----------------
__global__ __launch_bounds__(256) void k_norm(
    const float* __restrict__ edge_fea, const int* __restrict__ eidx,
    const int* __restrict__ batch, const float* __restrict__ stats,
    const float* __restrict__ gamma_s, const float* __restrict__ beta_s,
    const float* __restrict__ gamma_v, float* __restrict__ out) {
  __shared__ float meanL[16], invsL[16], invvL[16];
  __shared__ int gL[16];
  const int t = threadIdx.x;
  const int e0 = blockIdx.x * 16;
  if (t < 16) {
    float c = 0.f, a = 0.f, b = 0.f, d = 0.f;
    for (int q = 0; q < 64; ++q) {
      const float* p = stats + (size_t)q * 64 + t * 4;
      c += p[0]; a += p[1]; b += p[2]; d += p[3];
    }
    float cnt = fmaxf(c, 1.0f);
    float m = a / (cnt * 128.0f);
    float var = b / (cnt * 128.0f) - m * m;
    meanL[t] = m;
    invsL[t] = rsqrtf(var + 1e-5f);
    invvL[t] = rsqrtf(d / (cnt * 192.0f) + 1e-5f);
  }
  if (t >= 32 && t < 48) gL[t - 32] = batch[eidx[e0 + t - 32]];
  __syncthreads();
  for (int o = t; o < 16 * 80; o += 256) {
    int e = o / 80, q = o % 80;
    size_t idx = (size_t)(e0 + e) * 80 + q;
    float4 z = ((const float4*)out)[idx];
    float4 ef = ((const float4*)edge_fea)[idx];
    int g = gL[e];
    float4 r;
    if (q < 32) {
      int c = q * 4;
      r.x = (z.x - meanL[g]) * invsL[g] * gamma_s[c + 0] + beta_s[c + 0] + ef.x;
      r.y = (z.y - meanL[g]) * invsL[g] * gamma_s[c + 1] + beta_s[c + 1] + ef.y;
      r.z = (z.z - meanL[g]) * invsL[g] * gamma_s[c + 2] + beta_s[c + 2] + ef.z;
      r.w = (z.w - meanL[g]) * invsL[g] * gamma_s[c + 3] + beta_s[c + 3] + ef.w;
    } else {
      int cc = q * 4 - 128;
      r.x = z.x * invvL[g] * gamma_v[(cc + 0) / 3] + ef.x;
      r.y = z.y * invvL[g] * gamma_v[(cc + 1) / 3] + ef.y;
      r.z = z.z * invvL[g] * gamma_v[(cc + 2) / 3] + ef.z;
      r.w = z.w * invvL[g] * gamma_v[(cc + 3) / 3] + ef.w;
    }
    ((float4*)out)[idx] = r;
  }
}

extern "C" void kernel_launch(void* const* d_in, const int* in_sizes, int n_in,
                              void* d_out, int out_size, void* d_ws, size_t ws_size,
                              hipStream_t stream) {
  const float* node_fea = (const float*)d_in[0];
  const float* edge_oh  = (const float*)d_in[1];
  const float* edge_sh  = (const float*)d_in[2];
  const float* edge_fea = (const float*)d_in[3];
  const float* elen     = (const float*)d_in[4];
  const int*   eidx     = (const int*)d_in[5];
  const int*   batch    = (const int*)d_in[6];
  const float* Wsc_s    = (const float*)d_in[7];
  const float* Wsc_v    = (const float*)d_in[8];
  const float* Wpre0    = (const float*)d_in[9];
  const float* bpre0    = (const float*)d_in[10];
  const float* Wpre1    = (const float*)d_in[11];
  const float* Wss      = (const float*)d_in[12];
  const float* Wvs      = (const float*)d_in[13];
  const float* Wsv      = (const float*)d_in[14];
  const float* Wvv      = (const float*)d_in[15];
  const float* Wf1      = (const float*)d_in[16];
  const float* bf1      = (const float*)d_in[17];
  const float* Wf2      = (const float*)d_in[18];
  const float* bf2      = (const float*)d_in[19];
  const float* Wf3      = (const float*)d_in[20];
  const float* bf3      = (const float*)d_in[21];
  const float* Wpost0   = (const float*)d_in[22];
  const float* bpost0   = (const float*)d_in[23];
  const float* Wpost1   = (const float*)d_in[24];
  const float* gamma_s  = (const float*)d_in[25];
  const float* beta_s   = (const float*)d_in[26];
  const float* gamma_v  = (const float*)d_in[27];
  float* out = (float*)d_out;

  char* ws = (char*)d_ws;
  float* statsB = (float*)ws;               // [64 buckets][16 g][4]
  u16* wbf = (u16*)(ws + 16384);

  hipMemsetAsync(statsB, 0, 64 * 64 * sizeof(float), stream);
  k_prep<<<(OW_END + 255) / 256, 256, 0, stream>>>(
      Wsc_s, Wsc_v, Wpre0, Wpre1, Wss, Wvs, Wsv, Wvv,
      Wf1, Wf2, Wf3, Wpost0, Wpost1, wbf);
  const int nblk64 = (E_TOT + MEs - 1) / MEs;  // 1563
  k_sc<<<nblk64, 512, 0, stream>>>(edge_fea, edge_oh, wbf + OW_W2S, wbf + OW_BTV, out);
  k_chain<<<E_TOT / 32, 512, 0, stream>>>(node_fea, edge_sh, edge_fea, elen, eidx, batch,
                                          wbf, bpre0, bf1, bf2, bf3, bpost0, out, statsB);
  k_norm<<<E_TOT / 16, 256, 0, stream>>>(edge_fea, eidx, batch, statsB,
                                         gamma_s, beta_s, gamma_v, out);
}

// Round 13
// 855.337 us; speedup vs baseline: 1.7139x; 1.7139x over previous
//
#include <hip/hip_runtime.h>
#include <math.h>

typedef unsigned int u32;
typedef unsigned short u16;
typedef __attribute__((ext_vector_type(8))) short bf16x8;
typedef __attribute__((ext_vector_type(4))) float f32x4;

#define E_TOT 100000
constexpr int NS = 128, DIM = 320;

constexpr float SC_S_SCALE = 0.022097086912079608f;  // 1/sqrt(128*16)
constexpr float SC_V_SCALE = 0.03125f;               // 1/32
constexpr float INV_SQRT128 = 0.08838834764831845f;
constexpr float INV_8 = 0.125f;
constexpr float INV_S384 = 0.05103103630798288f;
constexpr float INV_24 = 0.041666666666666664f;
constexpr float INV_S192 = 0.07216878364870323f;
constexpr float RSQRT2 = 0.7071067811865476f;

#define MFMA __builtin_amdgcn_mfma_f32_16x16x32_bf16
#define F4Z (f32x4){0.f, 0.f, 0.f, 0.f}

__device__ __forceinline__ float sigmoidf_(float x) { return 1.0f / (1.0f + __expf(-x)); }
__device__ __forceinline__ float siluf_(float x) { return x * sigmoidf_(x); }
__device__ __forceinline__ float bf2f(u16 h) {
  u32 u = ((u32)h) << 16;
  return __builtin_bit_cast(float, u);
}
__device__ __forceinline__ u16 f2bf(float f) {
  u32 u = __builtin_bit_cast(u32, f);
  return (u16)((u + 0x7fffu + ((u >> 16) & 1u)) >> 16);
}
__device__ __forceinline__ void gl_lds16(const void* g, void* l) {
  __builtin_amdgcn_global_load_lds((const __attribute__((address_space(1))) u32*)g,
                                   (__attribute__((address_space(3))) u32*)l, 16, 0, 0);
}
__device__ __forceinline__ bf16x8 pack8(float4 r0, float4 r1, float s) {
  bf16x8 a;
  a[0] = (short)f2bf(r0.x * s); a[1] = (short)f2bf(r0.y * s);
  a[2] = (short)f2bf(r0.z * s); a[3] = (short)f2bf(r0.w * s);
  a[4] = (short)f2bf(r1.x * s); a[5] = (short)f2bf(r1.y * s);
  a[6] = (short)f2bf(r1.z * s); a[7] = (short)f2bf(r1.w * s);
  return a;
}
// swizzled bf16 LDS helpers (XOR byte bits 4-6 with row&7); rowB multiple of 128
__device__ __forceinline__ void stb(char* base, int row, int rowB, int colByte, u16 v) {
  *(u16*)(base + row * rowB + (colByte ^ ((row & 7) << 4))) = v;
}
__device__ __forceinline__ u16 ldbs(const char* base, int row, int rowB, int colByte) {
  return *(const u16*)(base + row * rowB + (colByte ^ ((row & 7) << 4)));
}
__device__ __forceinline__ bf16x8 ldb8(const char* base, int row, int rowB, int colByte) {
  return *(const bf16x8*)(base + row * rowB + (colByte ^ ((row & 7) << 4)));
}
__device__ __forceinline__ void stb16(char* base, int row, int rowB, int colByte, bf16x8 v) {
  *(bf16x8*)(base + row * rowB + (colByte ^ ((row & 7) << 4))) = v;
}

// ---------------- weight arena (element offsets) ----------------
#define OW_W2S   0        /* [128 u][2048 k=s*128+v]  (sc_s, SC_S_SCALE folded) */
#define OW_BTV   262144   /* [64 u][1024 k=s*64+v]    (sc_v, SC_V_SCALE folded) */
// fragment-linear: elem = (nt*(K/32)+kc)*512 + lane*8 + j
#define OW_PRE0  327680   /* N=128 K=128 */
#define OW_PRE1X 344064   /* N=192 K=192 block-diag */
#define OW_SS    380928   /* N=192 K=384 */
#define OW_VS    454656   /* N=192 K=192 (svh path) */
#define OW_SV    491520   /* N=64  K=384 */
#define OW_VVX   516096   /* N=192 K=576 block-diag */
#define OW_F1    626688   /* N=64  K=128 */
#define OW_F2    634880   /* N=64  K=64  */
#define OW_F3    638976   /* N=192 K=64  */
#define OW_P0    651264   /* N=128 K=128 */
#define OW_P1X   667648   /* N=192 K=192 block-diag */
#define OW_END   704512

// ---------------- K0: weight prep ----------------
__device__ __forceinline__ void frag_uc(int oo, int K, int& up, int& c) {
  int per = (K >> 5) << 9;
  int nt = oo / per, r = oo % per;
  int kc = r >> 9, r2 = r & 511;
  int ln = r2 >> 3, j = r2 & 7;
  up = nt * 16 + (ln & 15);
  c = kc * 32 + (ln >> 4) * 8 + j;
}

__global__ __launch_bounds__(256) void k_prep(
    const float* __restrict__ Wsc_s, const float* __restrict__ Wsc_v,
    const float* __restrict__ Wpre0, const float* __restrict__ Wpre1,
    const float* __restrict__ Wss, const float* __restrict__ Wvs,
    const float* __restrict__ Wsv, const float* __restrict__ Wvv,
    const float* __restrict__ Wf1, const float* __restrict__ Wf2,
    const float* __restrict__ Wf3, const float* __restrict__ Wpost0,
    const float* __restrict__ Wpost1, u16* __restrict__ dst) {
  int o = blockIdx.x * 256 + threadIdx.x;
  if (o >= OW_END) return;
  float v;
  int up, c;
  if (o < OW_BTV) {
    int u = o >> 11, k = o & 2047, s = k >> 7, vv = k & 127;
    v = Wsc_s[((size_t)(vv * 16 + s)) * 128 + u] * SC_S_SCALE;
  } else if (o < OW_PRE0) {
    int oo = o - OW_BTV; int u = oo >> 10, k = oo & 1023, s = k >> 6, vv = k & 63;
    v = Wsc_v[((size_t)(vv * 16 + s)) * 64 + u] * SC_V_SCALE;
  } else if (o < OW_PRE1X) {
    frag_uc(o - OW_PRE0, 128, up, c);
    v = Wpre0[c * 128 + up] * INV_SQRT128;
  } else if (o < OW_SS) {
    frag_uc(o - OW_PRE1X, 192, up, c);
    int u = up / 3, m = up % 3, vv = c / 3, mp = c % 3;
    v = (m == mp) ? Wpre1[vv * 64 + u] * INV_8 : 0.f;
  } else if (o < OW_VS) {
    frag_uc(o - OW_SS, 384, up, c);
    v = Wss[c * 192 + up] * (INV_S384 * RSQRT2);
  } else if (o < OW_SV) {
    frag_uc(o - OW_VS, 192, up, c);
    v = Wvs[c * 192 + up] * (INV_24 * RSQRT2);
  } else if (o < OW_VVX) {
    frag_uc(o - OW_SV, 384, up, c);
    v = Wsv[c * 64 + up] * (INV_S384 * RSQRT2);
  } else if (o < OW_F1) {
    frag_uc(o - OW_VVX, 576, up, c);
    int u = up / 3, m = up % 3, p = c / 192, r = c % 192, vv = r / 3, mp = r % 3;
    v = (m == mp) ? Wvv[(p * 64 + vv) * 64 + u] * (INV_S192 * RSQRT2) : 0.f;
  } else if (o < OW_F2) {
    frag_uc(o - OW_F1, 128, up, c);
    v = Wf1[c * 64 + up];
  } else if (o < OW_F3) {
    frag_uc(o - OW_F2, 64, up, c);
    v = Wf2[c * 64 + up];
  } else if (o < OW_P0) {
    frag_uc(o - OW_F3, 64, up, c);
    v = Wf3[c * 192 + up];
  } else if (o < OW_P1X) {
    frag_uc(o - OW_P0, 128, up, c);
    v = Wpost0[c * 128 + up] * INV_SQRT128;
  } else {
    frag_uc(o - OW_P1X, 192, up, c);
    int u = up / 3, m = up % 3, vv = c / 3, mp = c % 3;
    v = (m == mp) ? Wpost1[vv * 64 + u] * INV_8 : 0.f;
  }
  dst[o] = f2bf(v);
}

// ---------------- K1a: sc_s — M=128 edges/block (halved weight traffic) ----------------
__global__ __launch_bounds__(256, 2) void k_sc_s(
    const float* __restrict__ edge_fea, const float* __restrict__ ohp,
    const u16* __restrict__ W2s, float* __restrict__ out) {
  __shared__ char esB[32768];   // [128][256B] swizzled
  __shared__ float ohL[128][16];
  __shared__ char Bbuf[32768];  // [128u][256B] per s
  const int t = threadIdx.x, lane = t & 63, ww = t >> 6;
  const int l15 = lane & 15, q8 = lane >> 4, q4 = q8 << 2, cbl = q8 << 4;
  const int e0 = blockIdx.x * 128;
  const int nE = min(128, E_TOT - e0);

  for (int o = t; o < 2048; o += 256) {
    int c = o & 15, e = o >> 4;
    float4 r0 = make_float4(0.f, 0.f, 0.f, 0.f), r1 = r0;
    if (e < nE) {
      const float* src = edge_fea + (size_t)(e0 + e) * 320 + c * 8;
      r0 = *(const float4*)src; r1 = *(const float4*)(src + 4);
    }
    stb16(esB, e, 256, c * 16, pack8(r0, r1, 1.f));
  }
  for (int o = t; o < 2048; o += 256) {
    int e = o >> 4, s = o & 15;
    ohL[e][s] = (e < nE) ? ohp[(size_t)(e0 + e) * 16 + s] : 0.f;
  }
  __syncthreads();

  f32x4 acc[8][2];
  #pragma unroll
  for (int rt = 0; rt < 8; ++rt) { acc[rt][0] = F4Z; acc[rt][1] = F4Z; }
  for (int s = 0; s < 16; ++s) {
    const char* sb = (const char*)W2s + s * 256;
    #pragma unroll
    for (int it = 0; it < 8; ++it) {
      int n = it * 256 + t;
      int u = n >> 4, gp = n & 15, g = gp ^ (u & 7);
      gl_lds16(sb + (size_t)u * 4096 + g * 16, Bbuf + n * 16);
    }
    __syncthreads();
    f32x4 tmp[8][2];
    #pragma unroll
    for (int rt = 0; rt < 8; ++rt) { tmp[rt][0] = F4Z; tmp[rt][1] = F4Z; }
    #pragma unroll
    for (int ks = 0; ks < 4; ++ks) {
      bf16x8 b0 = ldb8(Bbuf, ww * 32 + l15, 256, ks * 64 + cbl);
      bf16x8 b1 = ldb8(Bbuf, ww * 32 + 16 + l15, 256, ks * 64 + cbl);
      #pragma unroll
      for (int rt = 0; rt < 8; ++rt) {
        bf16x8 a = ldb8(esB, rt * 16 + l15, 256, ks * 64 + cbl);
        tmp[rt][0] = MFMA(a, b0, tmp[rt][0], 0, 0, 0);
        tmp[rt][1] = MFMA(a, b1, tmp[rt][1], 0, 0, 0);
      }
    }
    #pragma unroll
    for (int rt = 0; rt < 8; ++rt)
      #pragma unroll
      for (int j = 0; j < 4; ++j) {
        float oh = ohL[rt * 16 + q4 + j][s];
        acc[rt][0][j] += oh * tmp[rt][0][j];
        acc[rt][1][j] += oh * tmp[rt][1][j];
      }
    __syncthreads();
  }
  #pragma unroll
  for (int rt = 0; rt < 8; ++rt)
    #pragma unroll
    for (int ct = 0; ct < 2; ++ct) {
      int u = ww * 32 + ct * 16 + l15;
      #pragma unroll
      for (int j = 0; j < 4; ++j) {
        int e = rt * 16 + q4 + j;
        if (e < nE) out[(size_t)(e0 + e) * DIM + u] = acc[rt][ct][j];
      }
    }
}

// ---------------- K1b: sc_v — M=64, small LDS, 4 blocks/CU ----------------
#define MEs 64
__global__ __launch_bounds__(256, 4) void k_sc_v(
    const float* __restrict__ edge_fea, const float* __restrict__ ohp,
    const u16* __restrict__ Btv, float* __restrict__ out) {
  __shared__ char evT[24576];   // [192 r=3e+m][128B] swizzled, col=v
  __shared__ float ohL[64][16];
  __shared__ char Bbuf[8192];
  const int t = threadIdx.x, lane = t & 63, ww = t >> 6;
  const int l15 = lane & 15, q8 = lane >> 4, q4 = q8 << 2, cbl = q8 << 4;
  const int e0 = blockIdx.x * MEs;
  const int nE = min(MEs, E_TOT - e0);

  for (int o = t; o < 64 * 24; o += 256) {
    int c = o % 24, e = o / 24;
    float4 r0 = make_float4(0.f, 0.f, 0.f, 0.f), r1 = r0;
    if (e < nE) {
      const float* src = edge_fea + (size_t)(e0 + e) * 320 + 128 + c * 8;
      r0 = *(const float4*)src; r1 = *(const float4*)(src + 4);
    }
    int base = c * 8;
    float vals[8] = {r0.x, r0.y, r0.z, r0.w, r1.x, r1.y, r1.z, r1.w};
    #pragma unroll
    for (int z = 0; z < 8; ++z) {
      int cc = base + z;
      stb(evT, 3 * e + cc % 3, 128, (cc / 3) * 2, f2bf(vals[z]));
    }
  }
  for (int o = t; o < 1024; o += 256) {
    int e = o >> 4, s = o & 15;
    ohL[e][s] = (e < nE) ? ohp[(size_t)(e0 + e) * 16 + s] : 0.f;
  }
  __syncthreads();

  f32x4 acc[12];
  #pragma unroll
  for (int i = 0; i < 12; ++i) acc[i] = F4Z;
  for (int s = 0; s < 16; ++s) {
    #pragma unroll
    for (int it = 0; it < 2; ++it) {
      int n = it * 256 + t;
      int u = n >> 3, gp = n & 7, g = gp ^ (u & 7);
      gl_lds16((const char*)Btv + (size_t)u * 2048 + s * 128 + g * 16, Bbuf + n * 16);
    }
    __syncthreads();
    f32x4 tmp[12];
    #pragma unroll
    for (int i = 0; i < 12; ++i) tmp[i] = F4Z;
    #pragma unroll
    for (int ks = 0; ks < 2; ++ks) {
      bf16x8 b = ldb8(Bbuf, ww * 16 + l15, 128, ks * 64 + cbl);
      #pragma unroll
      for (int rt = 0; rt < 12; ++rt) {
        bf16x8 a = ldb8(evT, rt * 16 + l15, 128, ks * 64 + cbl);
        tmp[rt] = MFMA(a, b, tmp[rt], 0, 0, 0);
      }
    }
    #pragma unroll
    for (int rt = 0; rt < 12; ++rt)
      #pragma unroll
      for (int j = 0; j < 4; ++j) {
        int r = rt * 16 + q4 + j;
        acc[rt][j] += ohL[r / 3][s] * tmp[rt][j];
      }
    __syncthreads();
  }
  int u = ww * 16 + l15;
  #pragma unroll
  for (int rt = 0; rt < 12; ++rt)
    #pragma unroll
    for (int j = 0; j < 4; ++j) {
      int r = rt * 16 + q4 + j, e = r / 3, m = r - e * 3;
      if (e < nE) out[(size_t)(e0 + e) * DIM + 128 + u * 3 + m] = acc[rt][j];
    }
}

// ---------------- K2: fused chain + stats, M=32, 512 thr, 2 blocks/CU (verified R9/R11) ----------------
#define A_SZ 78976
__global__ __launch_bounds__(512, 4) void k_chain(
    const float* __restrict__ node_fea, const float* __restrict__ edge_sh,
    const float* __restrict__ edge_fea, const float* __restrict__ elen,
    const int* __restrict__ eidx, const int* __restrict__ batch,
    const u16* __restrict__ wbf,
    const float* __restrict__ bpre0, const float* __restrict__ bf1,
    const float* __restrict__ bf2, const float* __restrict__ bf3,
    const float* __restrict__ bpost0, float* __restrict__ out,
    float* __restrict__ statsB) {
  __shared__ char AR[A_SZ];
  float* shF = (float*)(AR + 77824);  // [32][4]
  int* ijL = (int*)(AR + 78336);      // [2][32]
  float* sS  = (float*)(AR + 78592);  // [32] z-sum (s part)
  float* sS2 = (float*)(AR + 78720);  // [32] z2-sum (s part)
  float* sV  = (float*)(AR + 78848);  // [32] z2-sum (v part)
  const int t = threadIdx.x, lane = t & 63, wv = t >> 6;
  const int l15 = lane & 15, q8 = lane >> 4, q4 = q8 << 2, cbl = q8 << 4;
  const int e0 = blockIdx.x * 32;

#define SA(b) (AR + (b) * 8192)
#define VA(b) (AR + 24576 + (b) * 12288)
  char* wB = AR;
  char* zsB = AR + 12288;
  char* gateB = AR + 20480;
  char* zvB = AR + 24576;
  char* t1B = AR + 61440;   // svh K 128..191 during [BAR1c, BAR2a]; t1 after BAR2a
  char* hB = AR + 65536;
  char* elB = AR + 69632;   // elen during P1; svh K 0..127 after BAR1b

  if (t < 64) { int p = t >> 5, e = t & 31; ijL[p * 32 + e] = eidx[p * E_TOT + e0 + e]; }
  if (t >= 64 && t < 192) { int o = t - 64; shF[o] = edge_sh[(size_t)e0 * 4 + o]; }
  if (t >= 192 && t < 288) ((float*)(AR + 78592))[t - 192] = 0.f;
  __syncthreads();

  // ---- P0: staging ----
  for (int o = t; o < 1280; o += 512) {
    int c = o % 40, e = o / 40;
    const float* src = edge_fea + (size_t)(e0 + e) * 320 + c * 8;
    float4 r0 = *(const float4*)src, r1 = *(const float4*)(src + 4);
    bf16x8 v = pack8(r0, r1, 1.f);
    if (c < 16) stb16(SA(2), e, 256, c * 16, v);
    else        stb16(VA(2), e, 384, (c - 16) * 16, v);
  }
  for (int o = t; o < 2560; o += 512) {
    int c = o % 40, tmp = o / 40, e = tmp & 31, p = tmp >> 5;
    const float* src = node_fea + (size_t)ijL[p * 32 + e] * 320 + c * 8;
    float4 r0 = *(const float4*)src, r1 = *(const float4*)(src + 4);
    bf16x8 v = pack8(r0, r1, 1.f);
    if (c < 16) stb16(SA(p), e, 256, c * 16, v);
    else        stb16(VA(p), e, 384, (c - 16) * 16, v);
  }
  for (int o = t; o < 512; o += 512) {
    int c = o & 15, e = o >> 4;
    const float* src = elen + (size_t)(e0 + e) * 128 + c * 8;
    float4 r0 = *(const float4*)src, r1 = *(const float4*)(src + 4);
    stb16(elB, e, 256, c * 16, pack8(r0, r1, 1.f));
  }
  __syncthreads();

  // ---- P1: v-pre (w0-3) | s-pre (w4-5) | h1 (w6-7) ----
  f32x4 acc[8];
  #pragma unroll
  for (int a = 0; a < 8; ++a) acc[a] = F4Z;
  if (wv < 4) {
    for (int kc = 0; kc < 6; ++kc) {
      bf16x8 a0 = ldb8(VA(2), l15, 384, kc * 64 + cbl);
      bf16x8 a1 = ldb8(VA(2), 16 + l15, 384, kc * 64 + cbl);
      #pragma unroll
      for (int i = 0; i < 3; ++i) {
        int nt = wv * 3 + i;
        bf16x8 b = *(const bf16x8*)(wbf + OW_PRE1X + (((size_t)nt * 6 + kc) << 9) + lane * 8);
        acc[i] = MFMA(a0, b, acc[i], 0, 0, 0);
        acc[3 + i] = MFMA(a1, b, acc[3 + i], 0, 0, 0);
      }
    }
  } else if (wv < 6) {
    for (int kc = 0; kc < 4; ++kc) {
      bf16x8 a0 = ldb8(SA(2), l15, 256, kc * 64 + cbl);
      bf16x8 a1 = ldb8(SA(2), 16 + l15, 256, kc * 64 + cbl);
      #pragma unroll
      for (int i = 0; i < 4; ++i) {
        int nt = (wv - 4) * 4 + i;
        bf16x8 b = *(const bf16x8*)(wbf + OW_PRE0 + (((size_t)nt * 4 + kc) << 9) + lane * 8);
        acc[i] = MFMA(a0, b, acc[i], 0, 0, 0);
        acc[4 + i] = MFMA(a1, b, acc[4 + i], 0, 0, 0);
      }
    }
  } else {
    for (int kc = 0; kc < 4; ++kc) {
      bf16x8 a0 = ldb8(elB, l15, 256, kc * 64 + cbl);
      bf16x8 a1 = ldb8(elB, 16 + l15, 256, kc * 64 + cbl);
      #pragma unroll
      for (int i = 0; i < 2; ++i) {
        int nt = (wv - 6) * 2 + i;
        bf16x8 b = *(const bf16x8*)(wbf + OW_F1 + (((size_t)nt * 4 + kc) << 9) + lane * 8);
        acc[i] = MFMA(a0, b, acc[i], 0, 0, 0);
        acc[2 + i] = MFMA(a1, b, acc[2 + i], 0, 0, 0);
      }
    }
  }
  __syncthreads();  // BAR1a
  if (wv < 4) {
    #pragma unroll
    for (int mt = 0; mt < 2; ++mt)
      #pragma unroll
      for (int i = 0; i < 3; ++i) {
        int up = (wv * 3 + i) * 16 + l15;
        #pragma unroll
        for (int j = 0; j < 4; ++j)
          stb(VA(2), mt * 16 + q4 + j, 384, up * 2, f2bf(acc[mt * 3 + i][j]));
      }
  } else if (wv < 6) {
    #pragma unroll
    for (int i = 0; i < 4; ++i) {
      int u = ((wv - 4) * 4 + i) * 16 + l15;
      float bias = bpre0[u];
      #pragma unroll
      for (int mt = 0; mt < 2; ++mt)
        #pragma unroll
        for (int j = 0; j < 4; ++j)
          stb(SA(2), mt * 16 + q4 + j, 256, u * 2, f2bf(acc[mt * 4 + i][j] + bias));
    }
  } else {
    #pragma unroll
    for (int i = 0; i < 2; ++i) {
      int u = ((wv - 6) * 2 + i) * 16 + l15;
      float bias = bf1[u];
      #pragma unroll
      for (int mt = 0; mt < 2; ++mt)
        #pragma unroll
        for (int j = 0; j < 4; ++j)
          stb(hB, mt * 16 + q4 + j, 128, u * 2, f2bf(siluf_(acc[mt * 2 + i][j] + bias)));
    }
  }
  __syncthreads();  // BAR1b

  // ---- P1.5: svh[e][K] -> elB (K<128) / t1B (K>=128) ----
  for (int o = t; o < 32 * 192; o += 512) {
    int e = o / 192, K = o % 192;
    int src = K >> 6, kk = K & 63;
    const char* vb = VA(src);
    float x0 = bf2f(ldbs(vb, e, 384, (3 * kk + 0) * 2));
    float x1 = bf2f(ldbs(vb, e, 384, (3 * kk + 1) * 2));
    float x2 = bf2f(ldbs(vb, e, 384, (3 * kk + 2) * 2));
    float sv = x0 * shF[e * 4 + 1] + x1 * shF[e * 4 + 2] + x2 * shF[e * 4 + 3];
    if (K < 128) stb(elB, e, 256, K * 2, f2bf(sv));
    else stb(t1B, e, 128, (K - 128) * 2, f2bf(sv));
  }
  __syncthreads();  // BAR1c

  // ---- P2: out_s (w0-5, acc4) | t1 (w6-7, acc4) ; h2 (all, acc1) ----
  f32x4 os[4] = {F4Z, F4Z, F4Z, F4Z};
  f32x4 h2a = F4Z;
  {
    const int hmt = wv >> 2, hnt = wv & 3;
    #pragma unroll
    for (int kc = 0; kc < 2; ++kc) {
      bf16x8 a = ldb8(hB, hmt * 16 + l15, 128, kc * 64 + cbl);
      bf16x8 b = *(const bf16x8*)(wbf + OW_F2 + (((size_t)hnt * 2 + kc) << 9) + lane * 8);
      h2a = MFMA(a, b, h2a, 0, 0, 0);
    }
  }
  if (wv < 6) {
    for (int kc = 0; kc < 12; ++kc) {
      int buf = kc >> 2, cB = (kc & 3) * 64 + cbl;
      bf16x8 a0 = ldb8(SA(buf), l15, 256, cB);
      bf16x8 a1 = ldb8(SA(buf), 16 + l15, 256, cB);
      #pragma unroll
      for (int i = 0; i < 2; ++i) {
        int nt = wv * 2 + i;
        bf16x8 b = *(const bf16x8*)(wbf + OW_SS + (((size_t)nt * 12 + kc) << 9) + lane * 8);
        os[i] = MFMA(a0, b, os[i], 0, 0, 0);
        os[2 + i] = MFMA(a1, b, os[2 + i], 0, 0, 0);
      }
    }
    #pragma unroll
    for (int mt = 0; mt < 2; ++mt)
      #pragma unroll
      for (int i = 0; i < 2; ++i)
        #pragma unroll
        for (int j = 0; j < 4; ++j)
          os[mt * 2 + i][j] *= shF[(mt * 16 + q4 + j) * 4 + 0];
    for (int kc = 0; kc < 6; ++kc) {
      const char* sb_ = (kc < 4) ? elB : t1B;
      int rB = (kc < 4) ? 256 : 128;
      int cB = ((kc < 4) ? kc : (kc - 4)) * 64 + cbl;
      bf16x8 a0 = ldb8(sb_, l15, rB, cB);
      bf16x8 a1 = ldb8(sb_, 16 + l15, rB, cB);
      #pragma unroll
      for (int i = 0; i < 2; ++i) {
        int nt = wv * 2 + i;
        bf16x8 b = *(const bf16x8*)(wbf + OW_VS + (((size_t)nt * 6 + kc) << 9) + lane * 8);
        os[i] = MFMA(a0, b, os[i], 0, 0, 0);
        os[2 + i] = MFMA(a1, b, os[2 + i], 0, 0, 0);
      }
    }
  } else {
    for (int kc = 0; kc < 12; ++kc) {
      int buf = kc >> 2, cB = (kc & 3) * 64 + cbl;
      bf16x8 a0 = ldb8(SA(buf), l15, 256, cB);
      bf16x8 a1 = ldb8(SA(buf), 16 + l15, 256, cB);
      #pragma unroll
      for (int i = 0; i < 2; ++i) {
        int nt = (wv - 6) * 2 + i;
        bf16x8 b = *(const bf16x8*)(wbf + OW_SV + (((size_t)nt * 12 + kc) << 9) + lane * 8);
        os[i] = MFMA(a0, b, os[i], 0, 0, 0);
        os[2 + i] = MFMA(a1, b, os[2 + i], 0, 0, 0);
      }
    }
  }
  __syncthreads();  // BAR2a
  {
    const int hmt = wv >> 2;
    int u = (wv & 3) * 16 + l15;
    float bias = bf2[u];
    #pragma unroll
    for (int j = 0; j < 4; ++j)
      stb(hB, hmt * 16 + q4 + j, 128, u * 2, f2bf(siluf_(h2a[j] + bias)));
  }
  if (wv >= 6) {
    #pragma unroll
    for (int mt = 0; mt < 2; ++mt)
      #pragma unroll
      for (int i = 0; i < 2; ++i) {
        int u = ((wv - 6) * 2 + i) * 16 + l15;
        #pragma unroll
        for (int j = 0; j < 4; ++j)
          stb(t1B, mt * 16 + q4 + j, 128, u * 2, f2bf(os[mt * 2 + i][j]));
      }
  }
  __syncthreads();  // BAR2b

  // ---- P3: w = h2@Wf3 + bf3 ----
  {
    f32x4 wa[3] = {F4Z, F4Z, F4Z};
    const int mtw = wv >> 2;
    #pragma unroll
    for (int kc = 0; kc < 2; ++kc) {
      bf16x8 a = ldb8(hB, mtw * 16 + l15, 128, kc * 64 + cbl);
      #pragma unroll
      for (int i = 0; i < 3; ++i) {
        int nt = (wv & 3) * 3 + i;
        bf16x8 b = *(const bf16x8*)(wbf + OW_F3 + (((size_t)nt * 2 + kc) << 9) + lane * 8);
        wa[i] = MFMA(a, b, wa[i], 0, 0, 0);
      }
    }
    #pragma unroll
    for (int i = 0; i < 3; ++i) {
      int up = ((wv & 3) * 3 + i) * 16 + l15;
      float bias = bf3[up];
      #pragma unroll
      for (int j = 0; j < 4; ++j)
        stb(wB, mtw * 16 + q4 + j, 384, up * 2, f2bf(wa[i][j] + bias));
    }
  }
  __syncthreads();  // BAR3

  // ---- P4: gating (w0-5) + out_v MFMAs (all) ----
  if (wv < 6) {
    #pragma unroll
    for (int mt = 0; mt < 2; ++mt)
      #pragma unroll
      for (int i = 0; i < 2; ++i) {
        int up = (wv * 2 + i) * 16 + l15;
        #pragma unroll
        for (int j = 0; j < 4; ++j) {
          int e = mt * 16 + q4 + j;
          float w_ = bf2f(ldbs(wB, e, 384, up * 2));
          float o_ = os[mt * 2 + i][j];
          if (up < 128) stb(zsB, e, 256, up * 2, f2bf(siluf_(o_) * w_));
          else stb(gateB, e, 128, (up - 128) * 2, f2bf(sigmoidf_(o_) * w_));
        }
      }
  }
  f32x4 ov[3] = {F4Z, F4Z, F4Z};
  {
    const int mtv = wv >> 2;
    for (int p = 0; p < 3; ++p)
      for (int kc6 = 0; kc6 < 6; ++kc6) {
        int cB = kc6 * 64 + cbl;
        bf16x8 a = ldb8(VA(p), mtv * 16 + l15, 384, cB);
        int kcg = p * 6 + kc6;
        #pragma unroll
        for (int i = 0; i < 3; ++i) {
          int nt = (wv & 3) * 3 + i;
          bf16x8 b = *(const bf16x8*)(wbf + OW_VVX + (((size_t)nt * 18 + kcg) << 9) + lane * 8);
          ov[i] = MFMA(a, b, ov[i], 0, 0, 0);
        }
      }
  }
  __syncthreads();  // BAR4
  {
    const int mtv = wv >> 2;
    #pragma unroll
    for (int i = 0; i < 3; ++i) {
      int up = ((wv & 3) * 3 + i) * 16 + l15;
      int u = (up * 683) >> 11, m = up - 3 * u;
      #pragma unroll
      for (int j = 0; j < 4; ++j) {
        int e = mtv * 16 + q4 + j;
        float t1v = bf2f(ldbs(t1B, e, 128, u * 2));
        float g = bf2f(ldbs(gateB, e, 128, u * 2));
        float val = ov[i][j] * shF[e * 4 + 0] + t1v * shF[e * 4 + 1 + m];
        stb(zvB, e, 384, up * 2, f2bf(val * g));
      }
    }
  }
  __syncthreads();  // BAR5

  // ---- P5: post0 + post1, RMW onto sc in d_out + per-edge stats ----
  {
    f32x4 p0[2] = {F4Z, F4Z};
    #pragma unroll
    for (int kc = 0; kc < 4; ++kc) {
      int cB = kc * 64 + cbl;
      bf16x8 a0 = ldb8(zsB, l15, 256, cB);
      bf16x8 a1 = ldb8(zsB, 16 + l15, 256, cB);
      bf16x8 b = *(const bf16x8*)(wbf + OW_P0 + (((size_t)wv * 4 + kc) << 9) + lane * 8);
      p0[0] = MFMA(a0, b, p0[0], 0, 0, 0);
      p0[1] = MFMA(a1, b, p0[1], 0, 0, 0);
    }
    int u = wv * 16 + l15;
    float bias = bpost0[u];
    float s1p[8], s2p[8];
    #pragma unroll
    for (int mt = 0; mt < 2; ++mt)
      #pragma unroll
      for (int j = 0; j < 4; ++j) {
        size_t o = (size_t)(e0 + mt * 16 + q4 + j) * DIM + u;
        float z = out[o] + p0[mt][j] + bias;
        out[o] = z;
        s1p[mt * 4 + j] = z;
        s2p[mt * 4 + j] = z * z;
      }
    #pragma unroll
    for (int msk = 1; msk < 16; msk <<= 1)
      #pragma unroll
      for (int k = 0; k < 8; ++k) {
        s1p[k] += __shfl_xor(s1p[k], msk);
        s2p[k] += __shfl_xor(s2p[k], msk);
      }
    if (l15 == 0) {
      #pragma unroll
      for (int mt = 0; mt < 2; ++mt)
        #pragma unroll
        for (int j = 0; j < 4; ++j) {
          int e = mt * 16 + q4 + j;
          atomicAdd(&sS[e], s1p[mt * 4 + j]);
          atomicAdd(&sS2[e], s2p[mt * 4 + j]);
        }
    }
  }
  {
    f32x4 p1[3] = {F4Z, F4Z, F4Z};
    const int mtv = wv >> 2;
    #pragma unroll
    for (int kc = 0; kc < 6; ++kc) {
      int cB = kc * 64 + cbl;
      bf16x8 a = ldb8(zvB, mtv * 16 + l15, 384, cB);
      #pragma unroll
      for (int i = 0; i < 3; ++i) {
        int nt = (wv & 3) * 3 + i;
        bf16x8 b = *(const bf16x8*)(wbf + OW_P1X + (((size_t)nt * 6 + kc) << 9) + lane * 8);
        p1[i] = MFMA(a, b, p1[i], 0, 0, 0);
      }
    }
    float svp[4] = {0.f, 0.f, 0.f, 0.f};
    #pragma unroll
    for (int i = 0; i < 3; ++i) {
      int up = ((wv & 3) * 3 + i) * 16 + l15;
      #pragma unroll
      for (int j = 0; j < 4; ++j) {
        size_t o = (size_t)(e0 + mtv * 16 + q4 + j) * DIM + 128 + up;
        float z = out[o] + p1[i][j];
        out[o] = z;
        svp[j] += z * z;
      }
    }
    #pragma unroll
    for (int msk = 1; msk < 16; msk <<= 1)
      #pragma unroll
      for (int j = 0; j < 4; ++j) svp[j] += __shfl_xor(svp[j], msk);
    if (l15 == 0) {
      #pragma unroll
      for (int j = 0; j < 4; ++j)
        atomicAdd(&sV[mtv * 16 + q4 + j], svp[j]);
    }
  }
  __syncthreads();  // BAR6
  if (t < 32) {
    int g = batch[ijL[t]];
    float* sb = statsB + ((size_t)(blockIdx.x & 63)) * 64 + g * 4;
    atomicAdd(sb + 0, 1.0f);
    atomicAdd(sb + 1, sS[t]);
    atomicAdd(sb + 2, sS2[t]);
    atomicAdd(sb + 3, sV[t]);
  }
#undef SA
#undef VA
}

// ---------------- K4: normalize + residual (float4; reduces 64 stat buckets) ----------------
__global__ __launch_bounds__(256) void k_norm(
    const float* __restrict__ edge_fea, const int* __restrict__ eidx,
    const int* __restrict__ batch, const float* __restrict__ stats,
    const float* __restrict__ gamma_s, const float* __restrict__ beta_s,
    const float* __restrict__ gamma_v, float* __restrict__ out) {
  __shared__ float meanL[16], invsL[16], invvL[16];
  __shared__ int gL[16];
  const int t = threadIdx.x;
  const int e0 = blockIdx.x * 16;
  if (t < 16) {
    float c = 0.f, a = 0.f, b = 0.f, d = 0.f;
    for (int q = 0; q < 64; ++q) {
      const float* p = stats + (size_t)q * 64 + t * 4;
      c += p[0]; a += p[1]; b += p[2]; d += p[3];
    }
    float cnt = fmaxf(c, 1.0f);
    float m = a / (cnt * 128.0f);
    float var = b / (cnt * 128.0f) - m * m;
    meanL[t] = m;
    invsL[t] = rsqrtf(var + 1e-5f);
    invvL[t] = rsqrtf(d / (cnt * 192.0f) + 1e-5f);
  }
  if (t >= 32 && t < 48) gL[t - 32] = batch[eidx[e0 + t - 32]];
  __syncthreads();
  for (int o = t; o < 16 * 80; o += 256) {
    int e = o / 80, q = o % 80;
    size_t idx = (size_t)(e0 + e) * 80 + q;
    float4 z = ((const float4*)out)[idx];
    float4 ef = ((const float4*)edge_fea)[idx];
    int g = gL[e];
    float4 r;
    if (q < 32) {
      int c = q * 4;
      r.x = (z.x - meanL[g]) * invsL[g] * gamma_s[c + 0] + beta_s[c + 0] + ef.x;
      r.y = (z.y - meanL[g]) * invsL[g] * gamma_s[c + 1] + beta_s[c + 1] + ef.y;
      r.z = (z.z - meanL[g]) * invsL[g] * gamma_s[c + 2] + beta_s[c + 2] + ef.z;
      r.w = (z.w - meanL[g]) * invsL[g] * gamma_s[c + 3] + beta_s[c + 3] + ef.w;
    } else {
      int cc = q * 4 - 128;
      r.x = z.x * invvL[g] * gamma_v[(cc + 0) / 3] + ef.x;
      r.y = z.y * invvL[g] * gamma_v[(cc + 1) / 3] + ef.y;
      r.z = z.z * invvL[g] * gamma_v[(cc + 2) / 3] + ef.z;
      r.w = z.w * invvL[g] * gamma_v[(cc + 3) / 3] + ef.w;
    }
    ((float4*)out)[idx] = r;
  }
}

extern "C" void kernel_launch(void* const* d_in, const int* in_sizes, int n_in,
                              void* d_out, int out_size, void* d_ws, size_t ws_size,
                              hipStream_t stream) {
  const float* node_fea = (const float*)d_in[0];
  const float* edge_oh  = (const float*)d_in[1];
  const float* edge_sh  = (const float*)d_in[2];
  const float* edge_fea = (const float*)d_in[3];
  const float* elen     = (const float*)d_in[4];
  const int*   eidx     = (const int*)d_in[5];
  const int*   batch    = (const int*)d_in[6];
  const float* Wsc_s    = (const float*)d_in[7];
  const float* Wsc_v    = (const float*)d_in[8];
  const float* Wpre0    = (const float*)d_in[9];
  const float* bpre0    = (const float*)d_in[10];
  const float* Wpre1    = (const float*)d_in[11];
  const float* Wss      = (const float*)d_in[12];
  const float* Wvs      = (const float*)d_in[13];
  const float* Wsv      = (const float*)d_in[14];
  const float* Wvv      = (const float*)d_in[15];
  const float* Wf1      = (const float*)d_in[16];
  const float* bf1      = (const float*)d_in[17];
  const float* Wf2      = (const float*)d_in[18];
  const float* bf2      = (const float*)d_in[19];
  const float* Wf3      = (const float*)d_in[20];
  const float* bf3      = (const float*)d_in[21];
  const float* Wpost0   = (const float*)d_in[22];
  const float* bpost0   = (const float*)d_in[23];
  const float* Wpost1   = (const float*)d_in[24];
  const float* gamma_s  = (const float*)d_in[25];
  const float* beta_s   = (const float*)d_in[26];
  const float* gamma_v  = (const float*)d_in[27];
  float* out = (float*)d_out;

  char* ws = (char*)d_ws;
  float* statsB = (float*)ws;               // [64 buckets][16 g][4]
  u16* wbf = (u16*)(ws + 16384);

  hipMemsetAsync(statsB, 0, 64 * 64 * sizeof(float), stream);
  k_prep<<<(OW_END + 255) / 256, 256, 0, stream>>>(
      Wsc_s, Wsc_v, Wpre0, Wpre1, Wss, Wvs, Wsv, Wvv,
      Wf1, Wf2, Wf3, Wpost0, Wpost1, wbf);
  k_sc_s<<<(E_TOT + 127) / 128, 256, 0, stream>>>(edge_fea, edge_oh, wbf + OW_W2S, out);
  k_sc_v<<<(E_TOT + MEs - 1) / MEs, 256, 0, stream>>>(edge_fea, edge_oh, wbf + OW_BTV, out);
  k_chain<<<E_TOT / 32, 512, 0, stream>>>(node_fea, edge_sh, edge_fea, elen, eidx, batch,
                                          wbf, bpre0, bf1, bf2, bf3, bpost0, out, statsB);
  k_norm<<<E_TOT / 16, 256, 0, stream>>>(edge_fea, eidx, batch, statsB,
                                         gamma_s, beta_s, gamma_v, out);
}

// Round 14
// 667.987 us; speedup vs baseline: 2.1946x; 1.2805x over previous
//
#include <hip/hip_runtime.h>
#include <math.h>

typedef unsigned int u32;
typedef unsigned short u16;
typedef __attribute__((ext_vector_type(8))) short bf16x8;
typedef __attribute__((ext_vector_type(4))) float f32x4;

#define E_TOT 100000
constexpr int NS = 128, DIM = 320;

constexpr float SC_S_SCALE = 0.022097086912079608f;  // 1/sqrt(128*16)
constexpr float SC_V_SCALE = 0.03125f;               // 1/32
constexpr float INV_SQRT128 = 0.08838834764831845f;
constexpr float INV_8 = 0.125f;
constexpr float INV_S384 = 0.05103103630798288f;
constexpr float INV_24 = 0.041666666666666664f;
constexpr float INV_S192 = 0.07216878364870323f;
constexpr float RSQRT2 = 0.7071067811865476f;

#define MFMA __builtin_amdgcn_mfma_f32_16x16x32_bf16
#define F4Z (f32x4){0.f, 0.f, 0.f, 0.f}

__device__ __forceinline__ float sigmoidf_(float x) { return 1.0f / (1.0f + __expf(-x)); }
__device__ __forceinline__ float siluf_(float x) { return x * sigmoidf_(x); }
__device__ __forceinline__ float bf2f(u16 h) {
  u32 u = ((u32)h) << 16;
  return __builtin_bit_cast(float, u);
}
__device__ __forceinline__ u16 f2bf(float f) {
  u32 u = __builtin_bit_cast(u32, f);
  return (u16)((u + 0x7fffu + ((u >> 16) & 1u)) >> 16);
}
__device__ __forceinline__ void gl_lds16(const void* g, void* l) {
  __builtin_amdgcn_global_load_lds((const __attribute__((address_space(1))) u32*)g,
                                   (__attribute__((address_space(3))) u32*)l, 16, 0, 0);
}
__device__ __forceinline__ bf16x8 pack8(float4 r0, float4 r1, float s) {
  bf16x8 a;
  a[0] = (short)f2bf(r0.x * s); a[1] = (short)f2bf(r0.y * s);
  a[2] = (short)f2bf(r0.z * s); a[3] = (short)f2bf(r0.w * s);
  a[4] = (short)f2bf(r1.x * s); a[5] = (short)f2bf(r1.y * s);
  a[6] = (short)f2bf(r1.z * s); a[7] = (short)f2bf(r1.w * s);
  return a;
}
// non-temporal streaming helpers (bypass L2 fill -> keep weights resident)
__device__ __forceinline__ float4 ntload4(const float* p) {
  f32x4 v = __builtin_nontemporal_load((const f32x4*)p);
  return make_float4(v[0], v[1], v[2], v[3]);
}
__device__ __forceinline__ float ntload1(const float* p) {
  return __builtin_nontemporal_load(p);
}
__device__ __forceinline__ void ntstore1(float* p, float v) {
  __builtin_nontemporal_store(v, p);
}
// swizzled bf16 LDS helpers (XOR byte bits 4-6 with row&7); rowB multiple of 128
__device__ __forceinline__ void stb(char* base, int row, int rowB, int colByte, u16 v) {
  *(u16*)(base + row * rowB + (colByte ^ ((row & 7) << 4))) = v;
}
__device__ __forceinline__ u16 ldbs(const char* base, int row, int rowB, int colByte) {
  return *(const u16*)(base + row * rowB + (colByte ^ ((row & 7) << 4)));
}
__device__ __forceinline__ bf16x8 ldb8(const char* base, int row, int rowB, int colByte) {
  return *(const bf16x8*)(base + row * rowB + (colByte ^ ((row & 7) << 4)));
}
__device__ __forceinline__ void stb16(char* base, int row, int rowB, int colByte, bf16x8 v) {
  *(bf16x8*)(base + row * rowB + (colByte ^ ((row & 7) << 4))) = v;
}

// ---------------- weight arena (element offsets) ----------------
#define OW_W2S   0        /* [128 u][2048 k=s*128+v]  (sc_s, SC_S_SCALE folded) */
#define OW_BTV   262144   /* [64 u][1024 k=s*64+v]    (sc_v, SC_V_SCALE folded) */
// fragment-linear: elem = (nt*(K/32)+kc)*512 + lane*8 + j
#define OW_PRE0  327680   /* N=128 K=128 */
#define OW_PRE1X 344064   /* N=192 K=192 block-diag */
#define OW_SS    380928   /* N=192 K=384 */
#define OW_VS    454656   /* N=192 K=192 (svh path) */
#define OW_SV    491520   /* N=64  K=384 */
#define OW_VVX   516096   /* N=192 K=576 block-diag */
#define OW_F1    626688   /* N=64  K=128 */
#define OW_F2    634880   /* N=64  K=64  */
#define OW_F3    638976   /* N=192 K=64  */
#define OW_P0    651264   /* N=128 K=128 */
#define OW_P1X   667648   /* N=192 K=192 block-diag */
#define OW_END   704512

// ---------------- K0: weight prep ----------------
__device__ __forceinline__ void frag_uc(int oo, int K, int& up, int& c) {
  int per = (K >> 5) << 9;
  int nt = oo / per, r = oo % per;
  int kc = r >> 9, r2 = r & 511;
  int ln = r2 >> 3, j = r2 & 7;
  up = nt * 16 + (ln & 15);
  c = kc * 32 + (ln >> 4) * 8 + j;
}

__global__ __launch_bounds__(256) void k_prep(
    const float* __restrict__ Wsc_s, const float* __restrict__ Wsc_v,
    const float* __restrict__ Wpre0, const float* __restrict__ Wpre1,
    const float* __restrict__ Wss, const float* __restrict__ Wvs,
    const float* __restrict__ Wsv, const float* __restrict__ Wvv,
    const float* __restrict__ Wf1, const float* __restrict__ Wf2,
    const float* __restrict__ Wf3, const float* __restrict__ Wpost0,
    const float* __restrict__ Wpost1, u16* __restrict__ dst) {
  int o = blockIdx.x * 256 + threadIdx.x;
  if (o >= OW_END) return;
  float v;
  int up, c;
  if (o < OW_BTV) {
    int u = o >> 11, k = o & 2047, s = k >> 7, vv = k & 127;
    v = Wsc_s[((size_t)(vv * 16 + s)) * 128 + u] * SC_S_SCALE;
  } else if (o < OW_PRE0) {
    int oo = o - OW_BTV; int u = oo >> 10, k = oo & 1023, s = k >> 6, vv = k & 63;
    v = Wsc_v[((size_t)(vv * 16 + s)) * 64 + u] * SC_V_SCALE;
  } else if (o < OW_PRE1X) {
    frag_uc(o - OW_PRE0, 128, up, c);
    v = Wpre0[c * 128 + up] * INV_SQRT128;
  } else if (o < OW_SS) {
    frag_uc(o - OW_PRE1X, 192, up, c);
    int u = up / 3, m = up % 3, vv = c / 3, mp = c % 3;
    v = (m == mp) ? Wpre1[vv * 64 + u] * INV_8 : 0.f;
  } else if (o < OW_VS) {
    frag_uc(o - OW_SS, 384, up, c);
    v = Wss[c * 192 + up] * (INV_S384 * RSQRT2);
  } else if (o < OW_SV) {
    frag_uc(o - OW_VS, 192, up, c);
    v = Wvs[c * 192 + up] * (INV_24 * RSQRT2);
  } else if (o < OW_VVX) {
    frag_uc(o - OW_SV, 384, up, c);
    v = Wsv[c * 64 + up] * (INV_S384 * RSQRT2);
  } else if (o < OW_F1) {
    frag_uc(o - OW_VVX, 576, up, c);
    int u = up / 3, m = up % 3, p = c / 192, r = c % 192, vv = r / 3, mp = r % 3;
    v = (m == mp) ? Wvv[(p * 64 + vv) * 64 + u] * (INV_S192 * RSQRT2) : 0.f;
  } else if (o < OW_F2) {
    frag_uc(o - OW_F1, 128, up, c);
    v = Wf1[c * 64 + up];
  } else if (o < OW_F3) {
    frag_uc(o - OW_F2, 64, up, c);
    v = Wf2[c * 64 + up];
  } else if (o < OW_P0) {
    frag_uc(o - OW_F3, 64, up, c);
    v = Wf3[c * 192 + up];
  } else if (o < OW_P1X) {
    frag_uc(o - OW_P0, 128, up, c);
    v = Wpost0[c * 128 + up] * INV_SQRT128;
  } else {
    frag_uc(o - OW_P1X, 192, up, c);
    int u = up / 3, m = up % 3, vv = c / 3, mp = c % 3;
    v = (m == mp) ? Wpost1[vv * 64 + u] * INV_8 : 0.f;
  }
  dst[o] = f2bf(v);
}

// ---------------- K1: merged sc (verified R7/R9/R11) + non-temporal streaming ----------------
#define MEs 64
__global__ __launch_bounds__(256, 2) void k_sc(
    const float* __restrict__ edge_fea, const float* __restrict__ ohp,
    const u16* __restrict__ W2s, const u16* __restrict__ Btv,
    float* __restrict__ out) {
  __shared__ char esB[16384];   // [64][256B] swizzled
  __shared__ char evT[24576];   // [192 r=3e+m][128B] swizzled, col=v
  __shared__ float ohL[64][16];
  __shared__ char Bbuf[32768];
  const int t = threadIdx.x, lane = t & 63, ww = t >> 6;
  const int l15 = lane & 15, q8 = lane >> 4, q4 = q8 << 2, cbl = q8 << 4;
  const int e0 = blockIdx.x * MEs;
  const int nE = min(MEs, E_TOT - e0);

  for (int o = t; o < 2560; o += 256) {
    int c = o % 40, e = o / 40;
    float4 r0 = make_float4(0.f, 0.f, 0.f, 0.f), r1 = r0;
    if (e < nE) {
      const float* src = edge_fea + (size_t)(e0 + e) * 320 + c * 8;
      r0 = ntload4(src); r1 = ntload4(src + 4);
    }
    if (c < 16) stb16(esB, e, 256, c * 16, pack8(r0, r1, 1.f));
    else {
      int base = (c - 16) * 8;
      float vals[8] = {r0.x, r0.y, r0.z, r0.w, r1.x, r1.y, r1.z, r1.w};
      #pragma unroll
      for (int z = 0; z < 8; ++z) {
        int cc = base + z;
        stb(evT, 3 * e + cc % 3, 128, (cc / 3) * 2, f2bf(vals[z]));
      }
    }
  }
  for (int o = t; o < 1024; o += 256) {
    int e = o >> 4, s = o & 15;
    ohL[e][s] = (e < nE) ? ntload1(&ohp[(size_t)(e0 + e) * 16 + s]) : 0.f;
  }
  __syncthreads();

  {
    bf16x8 afh[4][4];
    #pragma unroll
    for (int rt = 0; rt < 4; ++rt)
      #pragma unroll
      for (int ks = 0; ks < 4; ++ks)
        afh[rt][ks] = ldb8(esB, rt * 16 + l15, 256, ks * 64 + cbl);
    f32x4 acc[8];
    #pragma unroll
    for (int i = 0; i < 8; ++i) acc[i] = F4Z;
    for (int s = 0; s < 16; ++s) {
      const char* sb = (const char*)W2s + s * 256;
      #pragma unroll
      for (int it = 0; it < 8; ++it) {
        int n = it * 256 + t;
        int u = n >> 4, gp = n & 15, g = gp ^ (u & 7);
        gl_lds16(sb + (size_t)u * 4096 + g * 16, Bbuf + n * 16);
      }
      __syncthreads();
      f32x4 tmp[8];
      #pragma unroll
      for (int i = 0; i < 8; ++i) tmp[i] = F4Z;
      #pragma unroll
      for (int ks = 0; ks < 4; ++ks) {
        bf16x8 b0 = ldb8(Bbuf, ww * 32 + l15, 256, ks * 64 + cbl);
        bf16x8 b1 = ldb8(Bbuf, ww * 32 + 16 + l15, 256, ks * 64 + cbl);
        #pragma unroll
        for (int rt = 0; rt < 4; ++rt) {
          tmp[rt * 2 + 0] = MFMA(afh[rt][ks], b0, tmp[rt * 2 + 0], 0, 0, 0);
          tmp[rt * 2 + 1] = MFMA(afh[rt][ks], b1, tmp[rt * 2 + 1], 0, 0, 0);
        }
      }
      #pragma unroll
      for (int rt = 0; rt < 4; ++rt)
        #pragma unroll
        for (int j = 0; j < 4; ++j) {
          float oh = ohL[rt * 16 + q4 + j][s];
          acc[rt * 2 + 0][j] += oh * tmp[rt * 2 + 0][j];
          acc[rt * 2 + 1][j] += oh * tmp[rt * 2 + 1][j];
        }
      __syncthreads();
    }
    #pragma unroll
    for (int rt = 0; rt < 4; ++rt)
      #pragma unroll
      for (int ct = 0; ct < 2; ++ct) {
        int u = ww * 32 + ct * 16 + l15;
        #pragma unroll
        for (int j = 0; j < 4; ++j) {
          int e = rt * 16 + q4 + j;
          if (e < nE) ntstore1(&out[(size_t)(e0 + e) * DIM + u], acc[rt * 2 + ct][j]);
        }
      }
  }

  {
    f32x4 acc[12];
    #pragma unroll
    for (int i = 0; i < 12; ++i) acc[i] = F4Z;
    for (int s = 0; s < 16; ++s) {
      #pragma unroll
      for (int it = 0; it < 2; ++it) {
        int n = it * 256 + t;
        int u = n >> 3, gp = n & 7, g = gp ^ (u & 7);
        gl_lds16((const char*)Btv + (size_t)u * 2048 + s * 128 + g * 16, Bbuf + n * 16);
      }
      __syncthreads();
      f32x4 tmp[12];
      #pragma unroll
      for (int i = 0; i < 12; ++i) tmp[i] = F4Z;
      #pragma unroll
      for (int ks = 0; ks < 2; ++ks) {
        bf16x8 b = ldb8(Bbuf, ww * 16 + l15, 128, ks * 64 + cbl);
        #pragma unroll
        for (int rt = 0; rt < 12; ++rt) {
          bf16x8 a = ldb8(evT, rt * 16 + l15, 128, ks * 64 + cbl);
          tmp[rt] = MFMA(a, b, tmp[rt], 0, 0, 0);
        }
      }
      #pragma unroll
      for (int rt = 0; rt < 12; ++rt)
        #pragma unroll
        for (int j = 0; j < 4; ++j) {
          int r = rt * 16 + q4 + j;
          acc[rt][j] += ohL[r / 3][s] * tmp[rt][j];
        }
      __syncthreads();
    }
    int u = ww * 16 + l15;
    #pragma unroll
    for (int rt = 0; rt < 12; ++rt)
      #pragma unroll
      for (int j = 0; j < 4; ++j) {
        int r = rt * 16 + q4 + j, e = r / 3, m = r - e * 3;
        if (e < nE) ntstore1(&out[(size_t)(e0 + e) * DIM + 128 + u * 3 + m], acc[rt][j]);
      }
  }
}

// ---------------- K2: fused chain + stats, M=32, 512 thr, 2 blocks/CU (verified R9/R11) ----------------
#define A_SZ 78976
__global__ __launch_bounds__(512, 4) void k_chain(
    const float* __restrict__ node_fea, const float* __restrict__ edge_sh,
    const float* __restrict__ edge_fea, const float* __restrict__ elen,
    const int* __restrict__ eidx, const int* __restrict__ batch,
    const u16* __restrict__ wbf,
    const float* __restrict__ bpre0, const float* __restrict__ bf1,
    const float* __restrict__ bf2, const float* __restrict__ bf3,
    const float* __restrict__ bpost0, float* __restrict__ out,
    float* __restrict__ statsB) {
  __shared__ char AR[A_SZ];
  float* shF = (float*)(AR + 77824);  // [32][4]
  int* ijL = (int*)(AR + 78336);      // [2][32]
  float* sS  = (float*)(AR + 78592);  // [32] z-sum (s part)
  float* sS2 = (float*)(AR + 78720);  // [32] z2-sum (s part)
  float* sV  = (float*)(AR + 78848);  // [32] z2-sum (v part)
  const int t = threadIdx.x, lane = t & 63, wv = t >> 6;
  const int l15 = lane & 15, q8 = lane >> 4, q4 = q8 << 2, cbl = q8 << 4;
  const int e0 = blockIdx.x * 32;

#define SA(b) (AR + (b) * 8192)
#define VA(b) (AR + 24576 + (b) * 12288)
  char* wB = AR;
  char* zsB = AR + 12288;
  char* gateB = AR + 20480;
  char* zvB = AR + 24576;
  char* t1B = AR + 61440;   // svh K 128..191 during [BAR1c, BAR2a]; t1 after BAR2a
  char* hB = AR + 65536;
  char* elB = AR + 69632;   // elen during P1; svh K 0..127 after BAR1b

  if (t < 64) { int p = t >> 5, e = t & 31; ijL[p * 32 + e] = eidx[p * E_TOT + e0 + e]; }
  if (t >= 64 && t < 192) { int o = t - 64; shF[o] = edge_sh[(size_t)e0 * 4 + o]; }
  if (t >= 192 && t < 288) ((float*)(AR + 78592))[t - 192] = 0.f;
  __syncthreads();

  // ---- P0: staging ----
  for (int o = t; o < 1280; o += 512) {
    int c = o % 40, e = o / 40;
    const float* src = edge_fea + (size_t)(e0 + e) * 320 + c * 8;
    float4 r0 = *(const float4*)src, r1 = *(const float4*)(src + 4);
    bf16x8 v = pack8(r0, r1, 1.f);
    if (c < 16) stb16(SA(2), e, 256, c * 16, v);
    else        stb16(VA(2), e, 384, (c - 16) * 16, v);
  }
  for (int o = t; o < 2560; o += 512) {
    int c = o % 40, tmp = o / 40, e = tmp & 31, p = tmp >> 5;
    const float* src = node_fea + (size_t)ijL[p * 32 + e] * 320 + c * 8;
    float4 r0 = *(const float4*)src, r1 = *(const float4*)(src + 4);
    bf16x8 v = pack8(r0, r1, 1.f);
    if (c < 16) stb16(SA(p), e, 256, c * 16, v);
    else        stb16(VA(p), e, 384, (c - 16) * 16, v);
  }
  for (int o = t; o < 512; o += 512) {
    int c = o & 15, e = o >> 4;
    const float* src = elen + (size_t)(e0 + e) * 128 + c * 8;
    float4 r0 = *(const float4*)src, r1 = *(const float4*)(src + 4);
    stb16(elB, e, 256, c * 16, pack8(r0, r1, 1.f));
  }
  __syncthreads();

  // ---- P1: v-pre (w0-3) | s-pre (w4-5) | h1 (w6-7) ----
  f32x4 acc[8];
  #pragma unroll
  for (int a = 0; a < 8; ++a) acc[a] = F4Z;
  if (wv < 4) {
    for (int kc = 0; kc < 6; ++kc) {
      bf16x8 a0 = ldb8(VA(2), l15, 384, kc * 64 + cbl);
      bf16x8 a1 = ldb8(VA(2), 16 + l15, 384, kc * 64 + cbl);
      #pragma unroll
      for (int i = 0; i < 3; ++i) {
        int nt = wv * 3 + i;
        bf16x8 b = *(const bf16x8*)(wbf + OW_PRE1X + (((size_t)nt * 6 + kc) << 9) + lane * 8);
        acc[i] = MFMA(a0, b, acc[i], 0, 0, 0);
        acc[3 + i] = MFMA(a1, b, acc[3 + i], 0, 0, 0);
      }
    }
  } else if (wv < 6) {
    for (int kc = 0; kc < 4; ++kc) {
      bf16x8 a0 = ldb8(SA(2), l15, 256, kc * 64 + cbl);
      bf16x8 a1 = ldb8(SA(2), 16 + l15, 256, kc * 64 + cbl);
      #pragma unroll
      for (int i = 0; i < 4; ++i) {
        int nt = (wv - 4) * 4 + i;
        bf16x8 b = *(const bf16x8*)(wbf + OW_PRE0 + (((size_t)nt * 4 + kc) << 9) + lane * 8);
        acc[i] = MFMA(a0, b, acc[i], 0, 0, 0);
        acc[4 + i] = MFMA(a1, b, acc[4 + i], 0, 0, 0);
      }
    }
  } else {
    for (int kc = 0; kc < 4; ++kc) {
      bf16x8 a0 = ldb8(elB, l15, 256, kc * 64 + cbl);
      bf16x8 a1 = ldb8(elB, 16 + l15, 256, kc * 64 + cbl);
      #pragma unroll
      for (int i = 0; i < 2; ++i) {
        int nt = (wv - 6) * 2 + i;
        bf16x8 b = *(const bf16x8*)(wbf + OW_F1 + (((size_t)nt * 4 + kc) << 9) + lane * 8);
        acc[i] = MFMA(a0, b, acc[i], 0, 0, 0);
        acc[2 + i] = MFMA(a1, b, acc[2 + i], 0, 0, 0);
      }
    }
  }
  __syncthreads();  // BAR1a
  if (wv < 4) {
    #pragma unroll
    for (int mt = 0; mt < 2; ++mt)
      #pragma unroll
      for (int i = 0; i < 3; ++i) {
        int up = (wv * 3 + i) * 16 + l15;
        #pragma unroll
        for (int j = 0; j < 4; ++j)
          stb(VA(2), mt * 16 + q4 + j, 384, up * 2, f2bf(acc[mt * 3 + i][j]));
      }
  } else if (wv < 6) {
    #pragma unroll
    for (int i = 0; i < 4; ++i) {
      int u = ((wv - 4) * 4 + i) * 16 + l15;
      float bias = bpre0[u];
      #pragma unroll
      for (int mt = 0; mt < 2; ++mt)
        #pragma unroll
        for (int j = 0; j < 4; ++j)
          stb(SA(2), mt * 16 + q4 + j, 256, u * 2, f2bf(acc[mt * 4 + i][j] + bias));
    }
  } else {
    #pragma unroll
    for (int i = 0; i < 2; ++i) {
      int u = ((wv - 6) * 2 + i) * 16 + l15;
      float bias = bf1[u];
      #pragma unroll
      for (int mt = 0; mt < 2; ++mt)
        #pragma unroll
        for (int j = 0; j < 4; ++j)
          stb(hB, mt * 16 + q4 + j, 128, u * 2, f2bf(siluf_(acc[mt * 2 + i][j] + bias)));
    }
  }
  __syncthreads();  // BAR1b

  // ---- P1.5: svh[e][K] -> elB (K<128) / t1B (K>=128) ----
  for (int o = t; o < 32 * 192; o += 512) {
    int e = o / 192, K = o % 192;
    int src = K >> 6, kk = K & 63;
    const char* vb = VA(src);
    float x0 = bf2f(ldbs(vb, e, 384, (3 * kk + 0) * 2));
    float x1 = bf2f(ldbs(vb, e, 384, (3 * kk + 1) * 2));
    float x2 = bf2f(ldbs(vb, e, 384, (3 * kk + 2) * 2));
    float sv = x0 * shF[e * 4 + 1] + x1 * shF[e * 4 + 2] + x2 * shF[e * 4 + 3];
    if (K < 128) stb(elB, e, 256, K * 2, f2bf(sv));
    else stb(t1B, e, 128, (K - 128) * 2, f2bf(sv));
  }
  __syncthreads();  // BAR1c

  // ---- P2: out_s (w0-5, acc4) | t1 (w6-7, acc4) ; h2 (all, acc1) ----
  f32x4 os[4] = {F4Z, F4Z, F4Z, F4Z};
  f32x4 h2a = F4Z;
  {
    const int hmt = wv >> 2, hnt = wv & 3;
    #pragma unroll
    for (int kc = 0; kc < 2; ++kc) {
      bf16x8 a = ldb8(hB, hmt * 16 + l15, 128, kc * 64 + cbl);
      bf16x8 b = *(const bf16x8*)(wbf + OW_F2 + (((size_t)hnt * 2 + kc) << 9) + lane * 8);
      h2a = MFMA(a, b, h2a, 0, 0, 0);
    }
  }
  if (wv < 6) {
    for (int kc = 0; kc < 12; ++kc) {
      int buf = kc >> 2, cB = (kc & 3) * 64 + cbl;
      bf16x8 a0 = ldb8(SA(buf), l15, 256, cB);
      bf16x8 a1 = ldb8(SA(buf), 16 + l15, 256, cB);
      #pragma unroll
      for (int i = 0; i < 2; ++i) {
        int nt = wv * 2 + i;
        bf16x8 b = *(const bf16x8*)(wbf + OW_SS + (((size_t)nt * 12 + kc) << 9) + lane * 8);
        os[i] = MFMA(a0, b, os[i], 0, 0, 0);
        os[2 + i] = MFMA(a1, b, os[2 + i], 0, 0, 0);
      }
    }
    #pragma unroll
    for (int mt = 0; mt < 2; ++mt)
      #pragma unroll
      for (int i = 0; i < 2; ++i)
        #pragma unroll
        for (int j = 0; j < 4; ++j)
          os[mt * 2 + i][j] *= shF[(mt * 16 + q4 + j) * 4 + 0];
    for (int kc = 0; kc < 6; ++kc) {
      const char* sb_ = (kc < 4) ? elB : t1B;
      int rB = (kc < 4) ? 256 : 128;
      int cB = ((kc < 4) ? kc : (kc - 4)) * 64 + cbl;
      bf16x8 a0 = ldb8(sb_, l15, rB, cB);
      bf16x8 a1 = ldb8(sb_, 16 + l15, rB, cB);
      #pragma unroll
      for (int i = 0; i < 2; ++i) {
        int nt = wv * 2 + i;
        bf16x8 b = *(const bf16x8*)(wbf + OW_VS + (((size_t)nt * 6 + kc) << 9) + lane * 8);
        os[i] = MFMA(a0, b, os[i], 0, 0, 0);
        os[2 + i] = MFMA(a1, b, os[2 + i], 0, 0, 0);
      }
    }
  } else {
    for (int kc = 0; kc < 12; ++kc) {
      int buf = kc >> 2, cB = (kc & 3) * 64 + cbl;
      bf16x8 a0 = ldb8(SA(buf), l15, 256, cB);
      bf16x8 a1 = ldb8(SA(buf), 16 + l15, 256, cB);
      #pragma unroll
      for (int i = 0; i < 2; ++i) {
        int nt = (wv - 6) * 2 + i;
        bf16x8 b = *(const bf16x8*)(wbf + OW_SV + (((size_t)nt * 12 + kc) << 9) + lane * 8);
        os[i] = MFMA(a0, b, os[i], 0, 0, 0);
        os[2 + i] = MFMA(a1, b, os[2 + i], 0, 0, 0);
      }
    }
  }
  __syncthreads();  // BAR2a
  {
    const int hmt = wv >> 2;
    int u = (wv & 3) * 16 + l15;
    float bias = bf2[u];
    #pragma unroll
    for (int j = 0; j < 4; ++j)
      stb(hB, hmt * 16 + q4 + j, 128, u * 2, f2bf(siluf_(h2a[j] + bias)));
  }
  if (wv >= 6) {
    #pragma unroll
    for (int mt = 0; mt < 2; ++mt)
      #pragma unroll
      for (int i = 0; i < 2; ++i) {
        int u = ((wv - 6) * 2 + i) * 16 + l15;
        #pragma unroll
        for (int j = 0; j < 4; ++j)
          stb(t1B, mt * 16 + q4 + j, 128, u * 2, f2bf(os[mt * 2 + i][j]));
      }
  }
  __syncthreads();  // BAR2b

  // ---- P3: w = h2@Wf3 + bf3 ----
  {
    f32x4 wa[3] = {F4Z, F4Z, F4Z};
    const int mtw = wv >> 2;
    #pragma unroll
    for (int kc = 0; kc < 2; ++kc) {
      bf16x8 a = ldb8(hB, mtw * 16 + l15, 128, kc * 64 + cbl);
      #pragma unroll
      for (int i = 0; i < 3; ++i) {
        int nt = (wv & 3) * 3 + i;
        bf16x8 b = *(const bf16x8*)(wbf + OW_F3 + (((size_t)nt * 2 + kc) << 9) + lane * 8);
        wa[i] = MFMA(a, b, wa[i], 0, 0, 0);
      }
    }
    #pragma unroll
    for (int i = 0; i < 3; ++i) {
      int up = ((wv & 3) * 3 + i) * 16 + l15;
      float bias = bf3[up];
      #pragma unroll
      for (int j = 0; j < 4; ++j)
        stb(wB, mtw * 16 + q4 + j, 384, up * 2, f2bf(wa[i][j] + bias));
    }
  }
  __syncthreads();  // BAR3

  // ---- P4: gating (w0-5) + out_v MFMAs (all) ----
  if (wv < 6) {
    #pragma unroll
    for (int mt = 0; mt < 2; ++mt)
      #pragma unroll
      for (int i = 0; i < 2; ++i) {
        int up = (wv * 2 + i) * 16 + l15;
        #pragma unroll
        for (int j = 0; j < 4; ++j) {
          int e = mt * 16 + q4 + j;
          float w_ = bf2f(ldbs(wB, e, 384, up * 2));
          float o_ = os[mt * 2 + i][j];
          if (up < 128) stb(zsB, e, 256, up * 2, f2bf(siluf_(o_) * w_));
          else stb(gateB, e, 128, (up - 128) * 2, f2bf(sigmoidf_(o_) * w_));
        }
      }
  }
  f32x4 ov[3] = {F4Z, F4Z, F4Z};
  {
    const int mtv = wv >> 2;
    for (int p = 0; p < 3; ++p)
      for (int kc6 = 0; kc6 < 6; ++kc6) {
        int cB = kc6 * 64 + cbl;
        bf16x8 a = ldb8(VA(p), mtv * 16 + l15, 384, cB);
        int kcg = p * 6 + kc6;
        #pragma unroll
        for (int i = 0; i < 3; ++i) {
          int nt = (wv & 3) * 3 + i;
          bf16x8 b = *(const bf16x8*)(wbf + OW_VVX + (((size_t)nt * 18 + kcg) << 9) + lane * 8);
          ov[i] = MFMA(a, b, ov[i], 0, 0, 0);
        }
      }
  }
  __syncthreads();  // BAR4
  {
    const int mtv = wv >> 2;
    #pragma unroll
    for (int i = 0; i < 3; ++i) {
      int up = ((wv & 3) * 3 + i) * 16 + l15;
      int u = (up * 683) >> 11, m = up - 3 * u;
      #pragma unroll
      for (int j = 0; j < 4; ++j) {
        int e = mtv * 16 + q4 + j;
        float t1v = bf2f(ldbs(t1B, e, 128, u * 2));
        float g = bf2f(ldbs(gateB, e, 128, u * 2));
        float val = ov[i][j] * shF[e * 4 + 0] + t1v * shF[e * 4 + 1 + m];
        stb(zvB, e, 384, up * 2, f2bf(val * g));
      }
    }
  }
  __syncthreads();  // BAR5

  // ---- P5: post0 + post1, RMW onto sc in d_out + per-edge stats ----
  {
    f32x4 p0[2] = {F4Z, F4Z};
    #pragma unroll
    for (int kc = 0; kc < 4; ++kc) {
      int cB = kc * 64 + cbl;
      bf16x8 a0 = ldb8(zsB, l15, 256, cB);
      bf16x8 a1 = ldb8(zsB, 16 + l15, 256, cB);
      bf16x8 b = *(const bf16x8*)(wbf + OW_P0 + (((size_t)wv * 4 + kc) << 9) + lane * 8);
      p0[0] = MFMA(a0, b, p0[0], 0, 0, 0);
      p0[1] = MFMA(a1, b, p0[1], 0, 0, 0);
    }
    int u = wv * 16 + l15;
    float bias = bpost0[u];
    float s1p[8], s2p[8];
    #pragma unroll
    for (int mt = 0; mt < 2; ++mt)
      #pragma unroll
      for (int j = 0; j < 4; ++j) {
        size_t o = (size_t)(e0 + mt * 16 + q4 + j) * DIM + u;
        float z = out[o] + p0[mt][j] + bias;
        out[o] = z;
        s1p[mt * 4 + j] = z;
        s2p[mt * 4 + j] = z * z;
      }
    #pragma unroll
    for (int msk = 1; msk < 16; msk <<= 1)
      #pragma unroll
      for (int k = 0; k < 8; ++k) {
        s1p[k] += __shfl_xor(s1p[k], msk);
        s2p[k] += __shfl_xor(s2p[k], msk);
      }
    if (l15 == 0) {
      #pragma unroll
      for (int mt = 0; mt < 2; ++mt)
        #pragma unroll
        for (int j = 0; j < 4; ++j) {
          int e = mt * 16 + q4 + j;
          atomicAdd(&sS[e], s1p[mt * 4 + j]);
          atomicAdd(&sS2[e], s2p[mt * 4 + j]);
        }
    }
  }
  {
    f32x4 p1[3] = {F4Z, F4Z, F4Z};
    const int mtv = wv >> 2;
    #pragma unroll
    for (int kc = 0; kc < 6; ++kc) {
      int cB = kc * 64 + cbl;
      bf16x8 a = ldb8(zvB, mtv * 16 + l15, 384, cB);
      #pragma unroll
      for (int i = 0; i < 3; ++i) {
        int nt = (wv & 3) * 3 + i;
        bf16x8 b = *(const bf16x8*)(wbf + OW_P1X + (((size_t)nt * 6 + kc) << 9) + lane * 8);
        p1[i] = MFMA(a, b, p1[i], 0, 0, 0);
      }
    }
    float svp[4] = {0.f, 0.f, 0.f, 0.f};
    #pragma unroll
    for (int i = 0; i < 3; ++i) {
      int up = ((wv & 3) * 3 + i) * 16 + l15;
      #pragma unroll
      for (int j = 0; j < 4; ++j) {
        size_t o = (size_t)(e0 + mtv * 16 + q4 + j) * DIM + 128 + up;
        float z = out[o] + p1[i][j];
        out[o] = z;
        svp[j] += z * z;
      }
    }
    #pragma unroll
    for (int msk = 1; msk < 16; msk <<= 1)
      #pragma unroll
      for (int j = 0; j < 4; ++j) svp[j] += __shfl_xor(svp[j], msk);
    if (l15 == 0) {
      #pragma unroll
      for (int j = 0; j < 4; ++j)
        atomicAdd(&sV[mtv * 16 + q4 + j], svp[j]);
    }
  }
  __syncthreads();  // BAR6
  if (t < 32) {
    int g = batch[ijL[t]];
    float* sb = statsB + ((size_t)(blockIdx.x & 63)) * 64 + g * 4;
    atomicAdd(sb + 0, 1.0f);
    atomicAdd(sb + 1, sS[t]);
    atomicAdd(sb + 2, sS2[t]);
    atomicAdd(sb + 3, sV[t]);
  }
#undef SA
#undef VA
}

// ---------------- K4: normalize + residual (float4; reduces 64 stat buckets) ----------------
__global__ __launch_bounds__(256) void k_norm(
    const float* __restrict__ edge_fea, const int* __restrict__ eidx,
    const int* __restrict__ batch, const float* __restrict__ stats,
    const float* __restrict__ gamma_s, const float* __restrict__ beta_s,
    const float* __restrict__ gamma_v, float* __restrict__ out) {
  __shared__ float meanL[16], invsL[16], invvL[16];
  __shared__ int gL[16];
  const int t = threadIdx.x;
  const int e0 = blockIdx.x * 16;
  if (t < 16) {
    float c = 0.f, a = 0.f, b = 0.f, d = 0.f;
    for (int q = 0; q < 64; ++q) {
      const float* p = stats + (size_t)q * 64 + t * 4;
      c += p[0]; a += p[1]; b += p[2]; d += p[3];
    }
    float cnt = fmaxf(c, 1.0f);
    float m = a / (cnt * 128.0f);
    float var = b / (cnt * 128.0f) - m * m;
    meanL[t] = m;
    invsL[t] = rsqrtf(var + 1e-5f);
    invvL[t] = rsqrtf(d / (cnt * 192.0f) + 1e-5f);
  }
  if (t >= 32 && t < 48) gL[t - 32] = batch[eidx[e0 + t - 32]];
  __syncthreads();
  for (int o = t; o < 16 * 80; o += 256) {
    int e = o / 80, q = o % 80;
    size_t idx = (size_t)(e0 + e) * 80 + q;
    float4 z = ((const float4*)out)[idx];
    float4 ef = ((const float4*)edge_fea)[idx];
    int g = gL[e];
    float4 r;
    if (q < 32) {
      int c = q * 4;
      r.x = (z.x - meanL[g]) * invsL[g] * gamma_s[c + 0] + beta_s[c + 0] + ef.x;
      r.y = (z.y - meanL[g]) * invsL[g] * gamma_s[c + 1] + beta_s[c + 1] + ef.y;
      r.z = (z.z - meanL[g]) * invsL[g] * gamma_s[c + 2] + beta_s[c + 2] + ef.z;
      r.w = (z.w - meanL[g]) * invsL[g] * gamma_s[c + 3] + beta_s[c + 3] + ef.w;
    } else {
      int cc = q * 4 - 128;
      r.x = z.x * invvL[g] * gamma_v[(cc + 0) / 3] + ef.x;
      r.y = z.y * invvL[g] * gamma_v[(cc + 1) / 3] + ef.y;
      r.z = z.z * invvL[g] * gamma_v[(cc + 2) / 3] + ef.z;
      r.w = z.w * invvL[g] * gamma_v[(cc + 3) / 3] + ef.w;
    }
    ((float4*)out)[idx] = r;
  }
}

extern "C" void kernel_launch(void* const* d_in, const int* in_sizes, int n_in,
                              void* d_out, int out_size, void* d_ws, size_t ws_size,
                              hipStream_t stream) {
  const float* node_fea = (const float*)d_in[0];
  const float* edge_oh  = (const float*)d_in[1];
  const float* edge_sh  = (const float*)d_in[2];
  const float* edge_fea = (const float*)d_in[3];
  const float* elen     = (const float*)d_in[4];
  const int*   eidx     = (const int*)d_in[5];
  const int*   batch    = (const int*)d_in[6];
  const float* Wsc_s    = (const float*)d_in[7];
  const float* Wsc_v    = (const float*)d_in[8];
  const float* Wpre0    = (const float*)d_in[9];
  const float* bpre0    = (const float*)d_in[10];
  const float* Wpre1    = (const float*)d_in[11];
  const float* Wss      = (const float*)d_in[12];
  const float* Wvs      = (const float*)d_in[13];
  const float* Wsv      = (const float*)d_in[14];
  const float* Wvv      = (const float*)d_in[15];
  const float* Wf1      = (const float*)d_in[16];
  const float* bf1      = (const float*)d_in[17];
  const float* Wf2      = (const float*)d_in[18];
  const float* bf2      = (const float*)d_in[19];
  const float* Wf3      = (const float*)d_in[20];
  const float* bf3      = (const float*)d_in[21];
  const float* Wpost0   = (const float*)d_in[22];
  const float* bpost0   = (const float*)d_in[23];
  const float* Wpost1   = (const float*)d_in[24];
  const float* gamma_s  = (const float*)d_in[25];
  const float* beta_s   = (const float*)d_in[26];
  const float* gamma_v  = (const float*)d_in[27];
  float* out = (float*)d_out;

  char* ws = (char*)d_ws;
  float* statsB = (float*)ws;               // [64 buckets][16 g][4]
  u16* wbf = (u16*)(ws + 16384);

  hipMemsetAsync(statsB, 0, 64 * 64 * sizeof(float), stream);
  k_prep<<<(OW_END + 255) / 256, 256, 0, stream>>>(
      Wsc_s, Wsc_v, Wpre0, Wpre1, Wss, Wvs, Wsv, Wvv,
      Wf1, Wf2, Wf3, Wpost0, Wpost1, wbf);
  const int nblk64 = (E_TOT + MEs - 1) / MEs;  // 1563
  k_sc<<<nblk64, 256, 0, stream>>>(edge_fea, edge_oh, wbf + OW_W2S, wbf + OW_BTV, out);
  k_chain<<<E_TOT / 32, 512, 0, stream>>>(node_fea, edge_sh, edge_fea, elen, eidx, batch,
                                          wbf, bpre0, bf1, bf2, bf3, bpost0, out, statsB);
  k_norm<<<E_TOT / 16, 256, 0, stream>>>(edge_fea, eidx, batch, statsB,
                                         gamma_s, beta_s, gamma_v, out);
}

// Round 15
// 648.651 us; speedup vs baseline: 2.2600x; 1.0298x over previous
//
#include <hip/hip_runtime.h>
#include <math.h>

typedef unsigned int u32;
typedef unsigned short u16;
typedef __attribute__((ext_vector_type(8))) short bf16x8;
typedef __attribute__((ext_vector_type(4))) float f32x4;

#define E_TOT 100000
constexpr int NS = 128, DIM = 320;

constexpr float SC_S_SCALE = 0.022097086912079608f;  // 1/sqrt(128*16)
constexpr float SC_V_SCALE = 0.03125f;               // 1/32
constexpr float INV_SQRT128 = 0.08838834764831845f;
constexpr float INV_8 = 0.125f;
constexpr float INV_S384 = 0.05103103630798288f;
constexpr float INV_24 = 0.041666666666666664f;
constexpr float INV_S192 = 0.07216878364870323f;
constexpr float RSQRT2 = 0.7071067811865476f;

#define MFMA __builtin_amdgcn_mfma_f32_16x16x32_bf16
#define F4Z (f32x4){0.f, 0.f, 0.f, 0.f}

__device__ __forceinline__ float sigmoidf_(float x) { return 1.0f / (1.0f + __expf(-x)); }
__device__ __forceinline__ float siluf_(float x) { return x * sigmoidf_(x); }
__device__ __forceinline__ float bf2f(u16 h) {
  u32 u = ((u32)h) << 16;
  return __builtin_bit_cast(float, u);
}
__device__ __forceinline__ u16 f2bf(float f) {
  u32 u = __builtin_bit_cast(u32, f);
  return (u16)((u + 0x7fffu + ((u >> 16) & 1u)) >> 16);
}
__device__ __forceinline__ void gl_lds16(const void* g, void* l) {
  __builtin_amdgcn_global_load_lds((const __attribute__((address_space(1))) u32*)g,
                                   (__attribute__((address_space(3))) u32*)l, 16, 0, 0);
}
__device__ __forceinline__ bf16x8 pack8(float4 r0, float4 r1, float s) {
  bf16x8 a;
  a[0] = (short)f2bf(r0.x * s); a[1] = (short)f2bf(r0.y * s);
  a[2] = (short)f2bf(r0.z * s); a[3] = (short)f2bf(r0.w * s);
  a[4] = (short)f2bf(r1.x * s); a[5] = (short)f2bf(r1.y * s);
  a[6] = (short)f2bf(r1.z * s); a[7] = (short)f2bf(r1.w * s);
  return a;
}
// swizzled bf16 LDS helpers (XOR byte bits 4-6 with row&7); rowB multiple of 128
__device__ __forceinline__ void stb(char* base, int row, int rowB, int colByte, u16 v) {
  *(u16*)(base + row * rowB + (colByte ^ ((row & 7) << 4))) = v;
}
__device__ __forceinline__ u16 ldbs(const char* base, int row, int rowB, int colByte) {
  return *(const u16*)(base + row * rowB + (colByte ^ ((row & 7) << 4)));
}
__device__ __forceinline__ bf16x8 ldb8(const char* base, int row, int rowB, int colByte) {
  return *(const bf16x8*)(base + row * rowB + (colByte ^ ((row & 7) << 4)));
}
__device__ __forceinline__ void stb16(char* base, int row, int rowB, int colByte, bf16x8 v) {
  *(bf16x8*)(base + row * rowB + (colByte ^ ((row & 7) << 4))) = v;
}

// ---------------- weight arena (element offsets) ----------------
#define OW_W2S   0        /* [128 u][2048 k=s*128+v]  (sc_s, SC_S_SCALE folded) */
#define OW_BTV   262144   /* [64 u][1024 k=s*64+v]    (sc_v, SC_V_SCALE folded) */
// fragment-linear: elem = (nt*(K/32)+kc)*512 + lane*8 + j
#define OW_PRE0  327680   /* N=128 K=128 */
#define OW_PRE1X 344064   /* N=192 K=192 block-diag */
#define OW_SS    380928   /* N=192 K=384 */
#define OW_VS    454656   /* N=192 K=192 (svh path) */
#define OW_SV    491520   /* N=64  K=384 */
#define OW_VVX   516096   /* N=192 K=576 block-diag */
#define OW_F1    626688   /* N=64  K=128 */
#define OW_F2    634880   /* N=64  K=64  */
#define OW_F3    638976   /* N=192 K=64  */
#define OW_P0    651264   /* N=128 K=128 */
#define OW_P1X   667648   /* N=192 K=192 block-diag */
#define OW_END   704512

// ---------------- K0: weight prep ----------------
__device__ __forceinline__ void frag_uc(int oo, int K, int& up, int& c) {
  int per = (K >> 5) << 9;
  int nt = oo / per, r = oo % per;
  int kc = r >> 9, r2 = r & 511;
  int ln = r2 >> 3, j = r2 & 7;
  up = nt * 16 + (ln & 15);
  c = kc * 32 + (ln >> 4) * 8 + j;
}

__global__ __launch_bounds__(256) void k_prep(
    const float* __restrict__ Wsc_s, const float* __restrict__ Wsc_v,
    const float* __restrict__ Wpre0, const float* __restrict__ Wpre1,
    const float* __restrict__ Wss, const float* __restrict__ Wvs,
    const float* __restrict__ Wsv, const float* __restrict__ Wvv,
    const float* __restrict__ Wf1, const float* __restrict__ Wf2,
    const float* __restrict__ Wf3, const float* __restrict__ Wpost0,
    const float* __restrict__ Wpost1, u16* __restrict__ dst) {
  int o = blockIdx.x * 256 + threadIdx.x;
  if (o >= OW_END) return;
  float v;
  int up, c;
  if (o < OW_BTV) {
    int u = o >> 11, k = o & 2047, s = k >> 7, vv = k & 127;
    v = Wsc_s[((size_t)(vv * 16 + s)) * 128 + u] * SC_S_SCALE;
  } else if (o < OW_PRE0) {
    int oo = o - OW_BTV; int u = oo >> 10, k = oo & 1023, s = k >> 6, vv = k & 63;
    v = Wsc_v[((size_t)(vv * 16 + s)) * 64 + u] * SC_V_SCALE;
  } else if (o < OW_PRE1X) {
    frag_uc(o - OW_PRE0, 128, up, c);
    v = Wpre0[c * 128 + up] * INV_SQRT128;
  } else if (o < OW_SS) {
    frag_uc(o - OW_PRE1X, 192, up, c);
    int u = up / 3, m = up % 3, vv = c / 3, mp = c % 3;
    v = (m == mp) ? Wpre1[vv * 64 + u] * INV_8 : 0.f;
  } else if (o < OW_VS) {
    frag_uc(o - OW_SS, 384, up, c);
    v = Wss[c * 192 + up] * (INV_S384 * RSQRT2);
  } else if (o < OW_SV) {
    frag_uc(o - OW_VS, 192, up, c);
    v = Wvs[c * 192 + up] * (INV_24 * RSQRT2);
  } else if (o < OW_VVX) {
    frag_uc(o - OW_SV, 384, up, c);
    v = Wsv[c * 64 + up] * (INV_S384 * RSQRT2);
  } else if (o < OW_F1) {
    frag_uc(o - OW_VVX, 576, up, c);
    int u = up / 3, m = up % 3, p = c / 192, r = c % 192, vv = r / 3, mp = r % 3;
    v = (m == mp) ? Wvv[(p * 64 + vv) * 64 + u] * (INV_S192 * RSQRT2) : 0.f;
  } else if (o < OW_F2) {
    frag_uc(o - OW_F1, 128, up, c);
    v = Wf1[c * 64 + up];
  } else if (o < OW_F3) {
    frag_uc(o - OW_F2, 64, up, c);
    v = Wf2[c * 64 + up];
  } else if (o < OW_P0) {
    frag_uc(o - OW_F3, 64, up, c);
    v = Wf3[c * 192 + up];
  } else if (o < OW_P1X) {
    frag_uc(o - OW_P0, 128, up, c);
    v = Wpost0[c * 128 + up] * INV_SQRT128;
  } else {
    frag_uc(o - OW_P1X, 192, up, c);
    int u = up / 3, m = up % 3, vv = c / 3, mp = c % 3;
    v = (m == mp) ? Wpost1[vv * 64 + u] * INV_8 : 0.f;
  }
  dst[o] = f2bf(v);
}

// ---------------- K1: merged sc (verified R7/R9) ----------------
#define MEs 64
__global__ __launch_bounds__(256, 2) void k_sc(
    const float* __restrict__ edge_fea, const float* __restrict__ ohp,
    const u16* __restrict__ W2s, const u16* __restrict__ Btv,
    float* __restrict__ out) {
  __shared__ char esB[16384];   // [64][256B] swizzled
  __shared__ char evT[24576];   // [192 r=3e+m][128B] swizzled, col=v
  __shared__ float ohL[64][16];
  __shared__ char Bbuf[32768];
  const int t = threadIdx.x, lane = t & 63, ww = t >> 6;
  const int l15 = lane & 15, q8 = lane >> 4, q4 = q8 << 2, cbl = q8 << 4;
  const int e0 = blockIdx.x * MEs;
  const int nE = min(MEs, E_TOT - e0);

  for (int o = t; o < 2560; o += 256) {
    int c = o % 40, e = o / 40;
    float4 r0 = make_float4(0.f, 0.f, 0.f, 0.f), r1 = r0;
    if (e < nE) {
      const float* src = edge_fea + (size_t)(e0 + e) * 320 + c * 8;
      r0 = *(const float4*)src; r1 = *(const float4*)(src + 4);
    }
    if (c < 16) stb16(esB, e, 256, c * 16, pack8(r0, r1, 1.f));
    else {
      int base = (c - 16) * 8;
      float vals[8] = {r0.x, r0.y, r0.z, r0.w, r1.x, r1.y, r1.z, r1.w};
      #pragma unroll
      for (int z = 0; z < 8; ++z) {
        int cc = base + z;
        stb(evT, 3 * e + cc % 3, 128, (cc / 3) * 2, f2bf(vals[z]));
      }
    }
  }
  for (int o = t; o < 1024; o += 256) {
    int e = o >> 4, s = o & 15;
    ohL[e][s] = (e < nE) ? ohp[(size_t)(e0 + e) * 16 + s] : 0.f;
  }
  __syncthreads();

  {
    bf16x8 afh[4][4];
    #pragma unroll
    for (int rt = 0; rt < 4; ++rt)
      #pragma unroll
      for (int ks = 0; ks < 4; ++ks)
        afh[rt][ks] = ldb8(esB, rt * 16 + l15, 256, ks * 64 + cbl);
    f32x4 acc[8];
    #pragma unroll
    for (int i = 0; i < 8; ++i) acc[i] = F4Z;
    for (int s = 0; s < 16; ++s) {
      const char* sb = (const char*)W2s + s * 256;
      #pragma unroll
      for (int it = 0; it < 8; ++it) {
        int n = it * 256 + t;
        int u = n >> 4, gp = n & 15, g = gp ^ (u & 7);
        gl_lds16(sb + (size_t)u * 4096 + g * 16, Bbuf + n * 16);
      }
      __syncthreads();
      f32x4 tmp[8];
      #pragma unroll
      for (int i = 0; i < 8; ++i) tmp[i] = F4Z;
      #pragma unroll
      for (int ks = 0; ks < 4; ++ks) {
        bf16x8 b0 = ldb8(Bbuf, ww * 32 + l15, 256, ks * 64 + cbl);
        bf16x8 b1 = ldb8(Bbuf, ww * 32 + 16 + l15, 256, ks * 64 + cbl);
        #pragma unroll
        for (int rt = 0; rt < 4; ++rt) {
          tmp[rt * 2 + 0] = MFMA(afh[rt][ks], b0, tmp[rt * 2 + 0], 0, 0, 0);
          tmp[rt * 2 + 1] = MFMA(afh[rt][ks], b1, tmp[rt * 2 + 1], 0, 0, 0);
        }
      }
      #pragma unroll
      for (int rt = 0; rt < 4; ++rt)
        #pragma unroll
        for (int j = 0; j < 4; ++j) {
          float oh = ohL[rt * 16 + q4 + j][s];
          acc[rt * 2 + 0][j] += oh * tmp[rt * 2 + 0][j];
          acc[rt * 2 + 1][j] += oh * tmp[rt * 2 + 1][j];
        }
      __syncthreads();
    }
    #pragma unroll
    for (int rt = 0; rt < 4; ++rt)
      #pragma unroll
      for (int ct = 0; ct < 2; ++ct) {
        int u = ww * 32 + ct * 16 + l15;
        #pragma unroll
        for (int j = 0; j < 4; ++j) {
          int e = rt * 16 + q4 + j;
          if (e < nE) out[(size_t)(e0 + e) * DIM + u] = acc[rt * 2 + ct][j];
        }
      }
  }

  {
    f32x4 acc[12];
    #pragma unroll
    for (int i = 0; i < 12; ++i) acc[i] = F4Z;
    for (int s = 0; s < 16; ++s) {
      #pragma unroll
      for (int it = 0; it < 2; ++it) {
        int n = it * 256 + t;
        int u = n >> 3, gp = n & 7, g = gp ^ (u & 7);
        gl_lds16((const char*)Btv + (size_t)u * 2048 + s * 128 + g * 16, Bbuf + n * 16);
      }
      __syncthreads();
      f32x4 tmp[12];
      #pragma unroll
      for (int i = 0; i < 12; ++i) tmp[i] = F4Z;
      #pragma unroll
      for (int ks = 0; ks < 2; ++ks) {
        bf16x8 b = ldb8(Bbuf, ww * 16 + l15, 128, ks * 64 + cbl);
        #pragma unroll
        for (int rt = 0; rt < 12; ++rt) {
          bf16x8 a = ldb8(evT, rt * 16 + l15, 128, ks * 64 + cbl);
          tmp[rt] = MFMA(a, b, tmp[rt], 0, 0, 0);
        }
      }
      #pragma unroll
      for (int rt = 0; rt < 12; ++rt)
        #pragma unroll
        for (int j = 0; j < 4; ++j) {
          int r = rt * 16 + q4 + j;
          acc[rt][j] += ohL[r / 3][s] * tmp[rt][j];
        }
      __syncthreads();
    }
    int u = ww * 16 + l15;
    #pragma unroll
    for (int rt = 0; rt < 12; ++rt)
      #pragma unroll
      for (int j = 0; j < 4; ++j) {
        int r = rt * 16 + q4 + j, e = r / 3, m = r - e * 3;
        if (e < nE) out[(size_t)(e0 + e) * DIM + 128 + u * 3 + m] = acc[rt][j];
      }
  }
}

// ---------------- K2: fused chain + stats, M=32, 512 thr, 2 blocks/CU (verified R9) ----------------
#define A_SZ 78976
__global__ __launch_bounds__(512, 4) void k_chain(
    const float* __restrict__ node_fea, const float* __restrict__ edge_sh,
    const float* __restrict__ edge_fea, const float* __restrict__ elen,
    const int* __restrict__ eidx, const int* __restrict__ batch,
    const u16* __restrict__ wbf,
    const float* __restrict__ bpre0, const float* __restrict__ bf1,
    const float* __restrict__ bf2, const float* __restrict__ bf3,
    const float* __restrict__ bpost0, float* __restrict__ out,
    float* __restrict__ statsB) {
  __shared__ char AR[A_SZ];
  float* shF = (float*)(AR + 77824);  // [32][4]
  int* ijL = (int*)(AR + 78336);      // [2][32]
  float* sS  = (float*)(AR + 78592);  // [32] z-sum (s part)
  float* sS2 = (float*)(AR + 78720);  // [32] z2-sum (s part)
  float* sV  = (float*)(AR + 78848);  // [32] z2-sum (v part)
  const int t = threadIdx.x, lane = t & 63, wv = t >> 6;
  const int l15 = lane & 15, q8 = lane >> 4, q4 = q8 << 2, cbl = q8 << 4;
  const int e0 = blockIdx.x * 32;

#define SA(b) (AR + (b) * 8192)
#define VA(b) (AR + 24576 + (b) * 12288)
  char* wB = AR;
  char* zsB = AR + 12288;
  char* gateB = AR + 20480;
  char* zvB = AR + 24576;
  char* t1B = AR + 61440;   // svh K 128..191 during [BAR1c, BAR2a]; t1 after BAR2a
  char* hB = AR + 65536;
  char* elB = AR + 69632;   // elen during P1; svh K 0..127 after BAR1b

  if (t < 64) { int p = t >> 5, e = t & 31; ijL[p * 32 + e] = eidx[p * E_TOT + e0 + e]; }
  if (t >= 64 && t < 192) { int o = t - 64; shF[o] = edge_sh[(size_t)e0 * 4 + o]; }
  if (t >= 192 && t < 288) ((float*)(AR + 78592))[t - 192] = 0.f;
  __syncthreads();

  // ---- P0: staging ----
  for (int o = t; o < 1280; o += 512) {
    int c = o % 40, e = o / 40;
    const float* src = edge_fea + (size_t)(e0 + e) * 320 + c * 8;
    float4 r0 = *(const float4*)src, r1 = *(const float4*)(src + 4);
    bf16x8 v = pack8(r0, r1, 1.f);
    if (c < 16) stb16(SA(2), e, 256, c * 16, v);
    else        stb16(VA(2), e, 384, (c - 16) * 16, v);
  }
  for (int o = t; o < 2560; o += 512) {
    int c = o % 40, tmp = o / 40, e = tmp & 31, p = tmp >> 5;
    const float* src = node_fea + (size_t)ijL[p * 32 + e] * 320 + c * 8;
    float4 r0 = *(const float4*)src, r1 = *(const float4*)(src + 4);
    bf16x8 v = pack8(r0, r1, 1.f);
    if (c < 16) stb16(SA(p), e, 256, c * 16, v);
    else        stb16(VA(p), e, 384, (c - 16) * 16, v);
  }
  for (int o = t; o < 512; o += 512) {
    int c = o & 15, e = o >> 4;
    const float* src = elen + (size_t)(e0 + e) * 128 + c * 8;
    float4 r0 = *(const float4*)src, r1 = *(const float4*)(src + 4);
    stb16(elB, e, 256, c * 16, pack8(r0, r1, 1.f));
  }
  __syncthreads();

  // ---- P1: v-pre (w0-3) | s-pre (w4-5) | h1 (w6-7) ----
  f32x4 acc[8];
  #pragma unroll
  for (int a = 0; a < 8; ++a) acc[a] = F4Z;
  if (wv < 4) {
    for (int kc = 0; kc < 6; ++kc) {
      bf16x8 a0 = ldb8(VA(2), l15, 384, kc * 64 + cbl);
      bf16x8 a1 = ldb8(VA(2), 16 + l15, 384, kc * 64 + cbl);
      #pragma unroll
      for (int i = 0; i < 3; ++i) {
        int nt = wv * 3 + i;
        bf16x8 b = *(const bf16x8*)(wbf + OW_PRE1X + (((size_t)nt * 6 + kc) << 9) + lane * 8);
        acc[i] = MFMA(a0, b, acc[i], 0, 0, 0);
        acc[3 + i] = MFMA(a1, b, acc[3 + i], 0, 0, 0);
      }
    }
  } else if (wv < 6) {
    for (int kc = 0; kc < 4; ++kc) {
      bf16x8 a0 = ldb8(SA(2), l15, 256, kc * 64 + cbl);
      bf16x8 a1 = ldb8(SA(2), 16 + l15, 256, kc * 64 + cbl);
      #pragma unroll
      for (int i = 0; i < 4; ++i) {
        int nt = (wv - 4) * 4 + i;
        bf16x8 b = *(const bf16x8*)(wbf + OW_PRE0 + (((size_t)nt * 4 + kc) << 9) + lane * 8);
        acc[i] = MFMA(a0, b, acc[i], 0, 0, 0);
        acc[4 + i] = MFMA(a1, b, acc[4 + i], 0, 0, 0);
      }
    }
  } else {
    for (int kc = 0; kc < 4; ++kc) {
      bf16x8 a0 = ldb8(elB, l15, 256, kc * 64 + cbl);
      bf16x8 a1 = ldb8(elB, 16 + l15, 256, kc * 64 + cbl);
      #pragma unroll
      for (int i = 0; i < 2; ++i) {
        int nt = (wv - 6) * 2 + i;
        bf16x8 b = *(const bf16x8*)(wbf + OW_F1 + (((size_t)nt * 4 + kc) << 9) + lane * 8);
        acc[i] = MFMA(a0, b, acc[i], 0, 0, 0);
        acc[2 + i] = MFMA(a1, b, acc[2 + i], 0, 0, 0);
      }
    }
  }
  __syncthreads();  // BAR1a
  if (wv < 4) {
    #pragma unroll
    for (int mt = 0; mt < 2; ++mt)
      #pragma unroll
      for (int i = 0; i < 3; ++i) {
        int up = (wv * 3 + i) * 16 + l15;
        #pragma unroll
        for (int j = 0; j < 4; ++j)
          stb(VA(2), mt * 16 + q4 + j, 384, up * 2, f2bf(acc[mt * 3 + i][j]));
      }
  } else if (wv < 6) {
    #pragma unroll
    for (int i = 0; i < 4; ++i) {
      int u = ((wv - 4) * 4 + i) * 16 + l15;
      float bias = bpre0[u];
      #pragma unroll
      for (int mt = 0; mt < 2; ++mt)
        #pragma unroll
        for (int j = 0; j < 4; ++j)
          stb(SA(2), mt * 16 + q4 + j, 256, u * 2, f2bf(acc[mt * 4 + i][j] + bias));
    }
  } else {
    #pragma unroll
    for (int i = 0; i < 2; ++i) {
      int u = ((wv - 6) * 2 + i) * 16 + l15;
      float bias = bf1[u];
      #pragma unroll
      for (int mt = 0; mt < 2; ++mt)
        #pragma unroll
        for (int j = 0; j < 4; ++j)
          stb(hB, mt * 16 + q4 + j, 128, u * 2, f2bf(siluf_(acc[mt * 2 + i][j] + bias)));
    }
  }
  __syncthreads();  // BAR1b

  // ---- P1.5: svh[e][K] -> elB (K<128) / t1B (K>=128) ----
  for (int o = t; o < 32 * 192; o += 512) {
    int e = o / 192, K = o % 192;
    int src = K >> 6, kk = K & 63;
    const char* vb = VA(src);
    float x0 = bf2f(ldbs(vb, e, 384, (3 * kk + 0) * 2));
    float x1 = bf2f(ldbs(vb, e, 384, (3 * kk + 1) * 2));
    float x2 = bf2f(ldbs(vb, e, 384, (3 * kk + 2) * 2));
    float sv = x0 * shF[e * 4 + 1] + x1 * shF[e * 4 + 2] + x2 * shF[e * 4 + 3];
    if (K < 128) stb(elB, e, 256, K * 2, f2bf(sv));
    else stb(t1B, e, 128, (K - 128) * 2, f2bf(sv));
  }
  __syncthreads();  // BAR1c

  // ---- P2: out_s (w0-5, acc4) | t1 (w6-7, acc4) ; h2 (all, acc1) ----
  f32x4 os[4] = {F4Z, F4Z, F4Z, F4Z};
  f32x4 h2a = F4Z;
  {
    const int hmt = wv >> 2, hnt = wv & 3;
    #pragma unroll
    for (int kc = 0; kc < 2; ++kc) {
      bf16x8 a = ldb8(hB, hmt * 16 + l15, 128, kc * 64 + cbl);
      bf16x8 b = *(const bf16x8*)(wbf + OW_F2 + (((size_t)hnt * 2 + kc) << 9) + lane * 8);
      h2a = MFMA(a, b, h2a, 0, 0, 0);
    }
  }
  if (wv < 6) {
    for (int kc = 0; kc < 12; ++kc) {
      int buf = kc >> 2, cB = (kc & 3) * 64 + cbl;
      bf16x8 a0 = ldb8(SA(buf), l15, 256, cB);
      bf16x8 a1 = ldb8(SA(buf), 16 + l15, 256, cB);
      #pragma unroll
      for (int i = 0; i < 2; ++i) {
        int nt = wv * 2 + i;
        bf16x8 b = *(const bf16x8*)(wbf + OW_SS + (((size_t)nt * 12 + kc) << 9) + lane * 8);
        os[i] = MFMA(a0, b, os[i], 0, 0, 0);
        os[2 + i] = MFMA(a1, b, os[2 + i], 0, 0, 0);
      }
    }
    #pragma unroll
    for (int mt = 0; mt < 2; ++mt)
      #pragma unroll
      for (int i = 0; i < 2; ++i)
        #pragma unroll
        for (int j = 0; j < 4; ++j)
          os[mt * 2 + i][j] *= shF[(mt * 16 + q4 + j) * 4 + 0];
    for (int kc = 0; kc < 6; ++kc) {
      const char* sb_ = (kc < 4) ? elB : t1B;
      int rB = (kc < 4) ? 256 : 128;
      int cB = ((kc < 4) ? kc : (kc - 4)) * 64 + cbl;
      bf16x8 a0 = ldb8(sb_, l15, rB, cB);
      bf16x8 a1 = ldb8(sb_, 16 + l15, rB, cB);
      #pragma unroll
      for (int i = 0; i < 2; ++i) {
        int nt = wv * 2 + i;
        bf16x8 b = *(const bf16x8*)(wbf + OW_VS + (((size_t)nt * 6 + kc) << 9) + lane * 8);
        os[i] = MFMA(a0, b, os[i], 0, 0, 0);
        os[2 + i] = MFMA(a1, b, os[2 + i], 0, 0, 0);
      }
    }
  } else {
    for (int kc = 0; kc < 12; ++kc) {
      int buf = kc >> 2, cB = (kc & 3) * 64 + cbl;
      bf16x8 a0 = ldb8(SA(buf), l15, 256, cB);
      bf16x8 a1 = ldb8(SA(buf), 16 + l15, 256, cB);
      #pragma unroll
      for (int i = 0; i < 2; ++i) {
        int nt = (wv - 6) * 2 + i;
        bf16x8 b = *(const bf16x8*)(wbf + OW_SV + (((size_t)nt * 12 + kc) << 9) + lane * 8);
        os[i] = MFMA(a0, b, os[i], 0, 0, 0);
        os[2 + i] = MFMA(a1, b, os[2 + i], 0, 0, 0);
      }
    }
  }
  __syncthreads();  // BAR2a
  {
    const int hmt = wv >> 2;
    int u = (wv & 3) * 16 + l15;
    float bias = bf2[u];
    #pragma unroll
    for (int j = 0; j < 4; ++j)
      stb(hB, hmt * 16 + q4 + j, 128, u * 2, f2bf(siluf_(h2a[j] + bias)));
  }
  if (wv >= 6) {
    #pragma unroll
    for (int mt = 0; mt < 2; ++mt)
      #pragma unroll
      for (int i = 0; i < 2; ++i) {
        int u = ((wv - 6) * 2 + i) * 16 + l15;
        #pragma unroll
        for (int j = 0; j < 4; ++j)
          stb(t1B, mt * 16 + q4 + j, 128, u * 2, f2bf(os[mt * 2 + i][j]));
      }
  }
  __syncthreads();  // BAR2b

  // ---- P3: w = h2@Wf3 + bf3 ----
  {
    f32x4 wa[3] = {F4Z, F4Z, F4Z};
    const int mtw = wv >> 2;
    #pragma unroll
    for (int kc = 0; kc < 2; ++kc) {
      bf16x8 a = ldb8(hB, mtw * 16 + l15, 128, kc * 64 + cbl);
      #pragma unroll
      for (int i = 0; i < 3; ++i) {
        int nt = (wv & 3) * 3 + i;
        bf16x8 b = *(const bf16x8*)(wbf + OW_F3 + (((size_t)nt * 2 + kc) << 9) + lane * 8);
        wa[i] = MFMA(a, b, wa[i], 0, 0, 0);
      }
    }
    #pragma unroll
    for (int i = 0; i < 3; ++i) {
      int up = ((wv & 3) * 3 + i) * 16 + l15;
      float bias = bf3[up];
      #pragma unroll
      for (int j = 0; j < 4; ++j)
        stb(wB, mtw * 16 + q4 + j, 384, up * 2, f2bf(wa[i][j] + bias));
    }
  }
  __syncthreads();  // BAR3

  // ---- P4: gating (w0-5) + out_v MFMAs (all) ----
  if (wv < 6) {
    #pragma unroll
    for (int mt = 0; mt < 2; ++mt)
      #pragma unroll
      for (int i = 0; i < 2; ++i) {
        int up = (wv * 2 + i) * 16 + l15;
        #pragma unroll
        for (int j = 0; j < 4; ++j) {
          int e = mt * 16 + q4 + j;
          float w_ = bf2f(ldbs(wB, e, 384, up * 2));
          float o_ = os[mt * 2 + i][j];
          if (up < 128) stb(zsB, e, 256, up * 2, f2bf(siluf_(o_) * w_));
          else stb(gateB, e, 128, (up - 128) * 2, f2bf(sigmoidf_(o_) * w_));
        }
      }
  }
  f32x4 ov[3] = {F4Z, F4Z, F4Z};
  {
    const int mtv = wv >> 2;
    for (int p = 0; p < 3; ++p)
      for (int kc6 = 0; kc6 < 6; ++kc6) {
        int cB = kc6 * 64 + cbl;
        bf16x8 a = ldb8(VA(p), mtv * 16 + l15, 384, cB);
        int kcg = p * 6 + kc6;
        #pragma unroll
        for (int i = 0; i < 3; ++i) {
          int nt = (wv & 3) * 3 + i;
          bf16x8 b = *(const bf16x8*)(wbf + OW_VVX + (((size_t)nt * 18 + kcg) << 9) + lane * 8);
          ov[i] = MFMA(a, b, ov[i], 0, 0, 0);
        }
      }
  }
  __syncthreads();  // BAR4
  {
    const int mtv = wv >> 2;
    #pragma unroll
    for (int i = 0; i < 3; ++i) {
      int up = ((wv & 3) * 3 + i) * 16 + l15;
      int u = (up * 683) >> 11, m = up - 3 * u;
      #pragma unroll
      for (int j = 0; j < 4; ++j) {
        int e = mtv * 16 + q4 + j;
        float t1v = bf2f(ldbs(t1B, e, 128, u * 2));
        float g = bf2f(ldbs(gateB, e, 128, u * 2));
        float val = ov[i][j] * shF[e * 4 + 0] + t1v * shF[e * 4 + 1 + m];
        stb(zvB, e, 384, up * 2, f2bf(val * g));
      }
    }
  }
  __syncthreads();  // BAR5

  // ---- P5: post0 + post1, RMW onto sc in d_out + per-edge stats ----
  {
    f32x4 p0[2] = {F4Z, F4Z};
    #pragma unroll
    for (int kc = 0; kc < 4; ++kc) {
      int cB = kc * 64 + cbl;
      bf16x8 a0 = ldb8(zsB, l15, 256, cB);
      bf16x8 a1 = ldb8(zsB, 16 + l15, 256, cB);
      bf16x8 b = *(const bf16x8*)(wbf + OW_P0 + (((size_t)wv * 4 + kc) << 9) + lane * 8);
      p0[0] = MFMA(a0, b, p0[0], 0, 0, 0);
      p0[1] = MFMA(a1, b, p0[1], 0, 0, 0);
    }
    int u = wv * 16 + l15;
    float bias = bpost0[u];
    float s1p[8], s2p[8];
    #pragma unroll
    for (int mt = 0; mt < 2; ++mt)
      #pragma unroll
      for (int j = 0; j < 4; ++j) {
        size_t o = (size_t)(e0 + mt * 16 + q4 + j) * DIM + u;
        float z = out[o] + p0[mt][j] + bias;
        out[o] = z;
        s1p[mt * 4 + j] = z;
        s2p[mt * 4 + j] = z * z;
      }
    #pragma unroll
    for (int msk = 1; msk < 16; msk <<= 1)
      #pragma unroll
      for (int k = 0; k < 8; ++k) {
        s1p[k] += __shfl_xor(s1p[k], msk);
        s2p[k] += __shfl_xor(s2p[k], msk);
      }
    if (l15 == 0) {
      #pragma unroll
      for (int mt = 0; mt < 2; ++mt)
        #pragma unroll
        for (int j = 0; j < 4; ++j) {
          int e = mt * 16 + q4 + j;
          atomicAdd(&sS[e], s1p[mt * 4 + j]);
          atomicAdd(&sS2[e], s2p[mt * 4 + j]);
        }
    }
  }
  {
    f32x4 p1[3] = {F4Z, F4Z, F4Z};
    const int mtv = wv >> 2;
    #pragma unroll
    for (int kc = 0; kc < 6; ++kc) {
      int cB = kc * 64 + cbl;
      bf16x8 a = ldb8(zvB, mtv * 16 + l15, 384, cB);
      #pragma unroll
      for (int i = 0; i < 3; ++i) {
        int nt = (wv & 3) * 3 + i;
        bf16x8 b = *(const bf16x8*)(wbf + OW_P1X + (((size_t)nt * 6 + kc) << 9) + lane * 8);
        p1[i] = MFMA(a, b, p1[i], 0, 0, 0);
      }
    }
    float svp[4] = {0.f, 0.f, 0.f, 0.f};
    #pragma unroll
    for (int i = 0; i < 3; ++i) {
      int up = ((wv & 3) * 3 + i) * 16 + l15;
      #pragma unroll
      for (int j = 0; j < 4; ++j) {
        size_t o = (size_t)(e0 + mtv * 16 + q4 + j) * DIM + 128 + up;
        float z = out[o] + p1[i][j];
        out[o] = z;
        svp[j] += z * z;
      }
    }
    #pragma unroll
    for (int msk = 1; msk < 16; msk <<= 1)
      #pragma unroll
      for (int j = 0; j < 4; ++j) svp[j] += __shfl_xor(svp[j], msk);
    if (l15 == 0) {
      #pragma unroll
      for (int j = 0; j < 4; ++j)
        atomicAdd(&sV[mtv * 16 + q4 + j], svp[j]);
    }
  }
  __syncthreads();  // BAR6
  if (t < 32) {
    int g = batch[ijL[t]];
    float* sb = statsB + ((size_t)(blockIdx.x & 63)) * 64 + g * 4;
    atomicAdd(sb + 0, 1.0f);
    atomicAdd(sb + 1, sS[t]);
    atomicAdd(sb + 2, sS2[t]);
    atomicAdd(sb + 3, sV[t]);
  }
#undef SA
#undef VA
}

// ---------------- K4: normalize + residual (float4; reduces 64 stat buckets) ----------------
__global__ __launch_bounds__(256) void k_norm(
    const float* __restrict__ edge_fea, const int* __restrict__ eidx,
    const int* __restrict__ batch, const float* __restrict__ stats,
    const float* __restrict__ gamma_s, const float* __restrict__ beta_s,
    const float* __restrict__ gamma_v, float* __restrict__ out) {
  __shared__ float meanL[16], invsL[16], invvL[16];
  __shared__ int gL[16];
  const int t = threadIdx.x;
  const int e0 = blockIdx.x * 16;
  if (t < 16) {
    float c = 0.f, a = 0.f, b = 0.f, d = 0.f;
    for (int q = 0; q < 64; ++q) {
      const float* p = stats + (size_t)q * 64 + t * 4;
      c += p[0]; a += p[1]; b += p[2]; d += p[3];
    }
    float cnt = fmaxf(c, 1.0f);
    float m = a / (cnt * 128.0f);
    float var = b / (cnt * 128.0f) - m * m;
    meanL[t] = m;
    invsL[t] = rsqrtf(var + 1e-5f);
    invvL[t] = rsqrtf(d / (cnt * 192.0f) + 1e-5f);
  }
  if (t >= 32 && t < 48) gL[t - 32] = batch[eidx[e0 + t - 32]];
  __syncthreads();
  for (int o = t; o < 16 * 80; o += 256) {
    int e = o / 80, q = o % 80;
    size_t idx = (size_t)(e0 + e) * 80 + q;
    float4 z = ((const float4*)out)[idx];
    float4 ef = ((const float4*)edge_fea)[idx];
    int g = gL[e];
    float4 r;
    if (q < 32) {
      int c = q * 4;
      r.x = (z.x - meanL[g]) * invsL[g] * gamma_s[c + 0] + beta_s[c + 0] + ef.x;
      r.y = (z.y - meanL[g]) * invsL[g] * gamma_s[c + 1] + beta_s[c + 1] + ef.y;
      r.z = (z.z - meanL[g]) * invsL[g] * gamma_s[c + 2] + beta_s[c + 2] + ef.z;
      r.w = (z.w - meanL[g]) * invsL[g] * gamma_s[c + 3] + beta_s[c + 3] + ef.w;
    } else {
      int cc = q * 4 - 128;
      r.x = z.x * invvL[g] * gamma_v[(cc + 0) / 3] + ef.x;
      r.y = z.y * invvL[g] * gamma_v[(cc + 1) / 3] + ef.y;
      r.z = z.z * invvL[g] * gamma_v[(cc + 2) / 3] + ef.z;
      r.w = z.w * invvL[g] * gamma_v[(cc + 3) / 3] + ef.w;
    }
    ((float4*)out)[idx] = r;
  }
}

extern "C" void kernel_launch(void* const* d_in, const int* in_sizes, int n_in,
                              void* d_out, int out_size, void* d_ws, size_t ws_size,
                              hipStream_t stream) {
  const float* node_fea = (const float*)d_in[0];
  const float* edge_oh  = (const float*)d_in[1];
  const float* edge_sh  = (const float*)d_in[2];
  const float* edge_fea = (const float*)d_in[3];
  const float* elen     = (const float*)d_in[4];
  const int*   eidx     = (const int*)d_in[5];
  const int*   batch    = (const int*)d_in[6];
  const float* Wsc_s    = (const float*)d_in[7];
  const float* Wsc_v    = (const float*)d_in[8];
  const float* Wpre0    = (const float*)d_in[9];
  const float* bpre0    = (const float*)d_in[10];
  const float* Wpre1    = (const float*)d_in[11];
  const float* Wss      = (const float*)d_in[12];
  const float* Wvs      = (const float*)d_in[13];
  const float* Wsv      = (const float*)d_in[14];
  const float* Wvv      = (const float*)d_in[15];
  const float* Wf1      = (const float*)d_in[16];
  const float* bf1      = (const float*)d_in[17];
  const float* Wf2      = (const float*)d_in[18];
  const float* bf2      = (const float*)d_in[19];
  const float* Wf3      = (const float*)d_in[20];
  const float* bf3      = (const float*)d_in[21];
  const float* Wpost0   = (const float*)d_in[22];
  const float* bpost0   = (const float*)d_in[23];
  const float* Wpost1   = (const float*)d_in[24];
  const float* gamma_s  = (const float*)d_in[25];
  const float* beta_s   = (const float*)d_in[26];
  const float* gamma_v  = (const float*)d_in[27];
  float* out = (float*)d_out;

  char* ws = (char*)d_ws;
  float* statsB = (float*)ws;               // [64 buckets][16 g][4]
  u16* wbf = (u16*)(ws + 16384);

  hipMemsetAsync(statsB, 0, 64 * 64 * sizeof(float), stream);
  k_prep<<<(OW_END + 255) / 256, 256, 0, stream>>>(
      Wsc_s, Wsc_v, Wpre0, Wpre1, Wss, Wvs, Wsv, Wvv,
      Wf1, Wf2, Wf3, Wpost0, Wpost1, wbf);
  const int nblk64 = (E_TOT + MEs - 1) / MEs;  // 1563
  k_sc<<<nblk64, 256, 0, stream>>>(edge_fea, edge_oh, wbf + OW_W2S, wbf + OW_BTV, out);
  k_chain<<<E_TOT / 32, 512, 0, stream>>>(node_fea, edge_sh, edge_fea, elen, eidx, batch,
                                          wbf, bpre0, bf1, bf2, bf3, bpost0, out, statsB);
  k_norm<<<E_TOT / 16, 256, 0, stream>>>(edge_fea, eidx, batch, statsB,
                                         gamma_s, beta_s, gamma_v, out);
}